// Round 3
// baseline (385.629 us; speedup 1.0000x reference)
//
#include <hip/hip_runtime.h>
#include <stdint.h>

// ---------------------------------------------------------------------------
// DistributedAttention on MI355X (gfx950)
//   q = x Wq^T + bq ; k = x Wk^T + bk ; v = x Wv^T + bv
//   P = softmax(q k^T / 8) ; out = P v Wo^T + bo
// Factorizations:
//   F  = Wo . Wv                 (2.1 GF, replaces the 17.2 GF v-proj)   [R7]
//   Vot= F . x^T per batch       ([H][S] bf16)                           [R7]
//   G  = Wq^T . Wk  (batch-indep, 2.1 GF)                                [R11]
//   qg = x . G + g0, g0 = Wk^T bq                                        [R11]
//   scores = qg . x^T + rowadd[i],  rowadd = x.(Wq^T bk) + bq.bk
//     -> eliminates one 8192x1024x1024 projection (17.2 GF) and k16
//        entirely (32 MB traffic). Error-neutral: qg carries ~0.44% rel
//        err vs q,k's 0.35% each; dot-err identical (~0.5% of scores).
//   P_un = exp(scores / 8)       (bf16 + atomic fp32 rowsums)
//   out  = (P_un . Vot^T)/rowsum + bfinal,  bfinal = bo + Wo.bv
// R11 dispatches: cvt_all -> gemm_gf (Gt,F,rowadd) -> gemm_qgv (qg+Vot)
//   -> scores (gemm_bt<3>, 128^2 proven path) -> final (gemm8p 128x256
//   phase-split, unchanged from R10).
// ---------------------------------------------------------------------------

typedef __bf16 bf16x8 __attribute__((ext_vector_type(8)));
typedef float  f32x4  __attribute__((ext_vector_type(4)));

__device__ __forceinline__ unsigned short f32_to_bf16_rne(float f) {
    uint32_t u = __builtin_bit_cast(uint32_t, f);
    uint32_t r = (u + 0x7FFFu + ((u >> 16) & 1u)) >> 16;
    return (unsigned short)r;
}

__device__ __forceinline__ float bf16_to_f32(unsigned short s) {
    return __builtin_bit_cast(float, (uint32_t)s << 16);
}

#define BM 128
#define BN 128
#define BK 64

// ---------------------------------------------------------------------------
// One-dispatch prep, 10017 blocks:
//   [0,8192)        x fp32 -> x16 bf16
//   [8192,9216)     Wo straight convert -> w16 slot 2
//   [9216,9984)     WqT, WkT, WvT 64x64-tile transposes -> slots 0,1,3
//   [9984,10000)    bfinal = bo + Wo.bv
//   [10000,10004)   g0 = Wk^T bq   (per-col dot, coalesced over j)
//   [10004,10008)   u  = Wq^T bk
//   [10008]         bqbk = dot(bq,bk)
//   [10009,10017)   zero rsum
// ---------------------------------------------------------------------------
__global__ __launch_bounds__(256) void cvt_all(
    const float* __restrict__ x,
    const float* __restrict__ Wq, const float* __restrict__ Wk,
    const float* __restrict__ Wo, const float* __restrict__ Wv,
    const float* __restrict__ bq, const float* __restrict__ bk,
    const float* __restrict__ bv, const float* __restrict__ bo,
    unsigned short* __restrict__ x16, unsigned short* __restrict__ w16,
    float* __restrict__ rsum, float* __restrict__ bfinal,
    float* __restrict__ g0, float* __restrict__ u, float* __restrict__ bqbk)
{
    const int b = blockIdx.x, tid = threadIdx.x;
    if (b < 8192) {
        int i = (b * 256 + tid) * 4;
        float4 v = *(const float4*)(x + i);
        ushort4 o;
        o.x = f32_to_bf16_rne(v.x); o.y = f32_to_bf16_rne(v.y);
        o.z = f32_to_bf16_rne(v.z); o.w = f32_to_bf16_rne(v.w);
        *(ushort4*)(x16 + i) = o;
    } else if (b < 9216) {
        int i = ((b - 8192) * 256 + tid) * 4;
        float4 v = *(const float4*)(Wo + i);
        ushort4 o;
        o.x = f32_to_bf16_rne(v.x); o.y = f32_to_bf16_rne(v.y);
        o.z = f32_to_bf16_rne(v.z); o.w = f32_to_bf16_rne(v.w);
        *(ushort4*)(w16 + (size_t)2 * 1048576 + i) = o;
    } else if (b < 9984) {
        // transpose one 64x64 tile of {Wq,Wk,Wv} into w16 slot {0,1,3}
        __shared__ unsigned short tl[64 * 68];   // [c][r], stride 68
        int t = b - 9216;
        int which = t >> 8;                      // 0:Wq 1:Wk 2:Wv
        const float* src = which == 0 ? Wq : which == 1 ? Wk : Wv;
        size_t slot = which == 0 ? 0 : which == 1 ? 1 : 3;
        int tile = t & 255, tr = tile >> 4, tc = tile & 15;
        #pragma unroll
        for (int it = 0; it < 4; ++it) {
            int r  = it * 16 + (tid >> 4);
            int c0 = (tid & 15) * 4;
            float4 v = *(const float4*)(src + (size_t)(tr * 64 + r) * 1024 + tc * 64 + c0);
            tl[(c0 + 0) * 68 + r] = f32_to_bf16_rne(v.x);
            tl[(c0 + 1) * 68 + r] = f32_to_bf16_rne(v.y);
            tl[(c0 + 2) * 68 + r] = f32_to_bf16_rne(v.z);
            tl[(c0 + 3) * 68 + r] = f32_to_bf16_rne(v.w);
        }
        __syncthreads();
        #pragma unroll
        for (int it = 0; it < 4; ++it) {
            int c  = it * 16 + (tid >> 4);
            int r0 = (tid & 15) * 4;
            ushort4 o;
            o.x = tl[c * 68 + r0 + 0]; o.y = tl[c * 68 + r0 + 1];
            o.z = tl[c * 68 + r0 + 2]; o.w = tl[c * 68 + r0 + 3];
            *(ushort4*)(w16 + slot * 1048576 + (size_t)(tc * 64 + c) * 1024 + tr * 64 + r0) = o;
        }
    } else if (b < 10000) {
        // bfinal[row] = bo[row] + dot(Wo[row,:], bv)
        int bb = b - 9984;
        int lane = tid & 63, wv_ = tid >> 6;
        int rowBase = bb * 64 + wv_ * 16;
        for (int rr = 0; rr < 16; ++rr) {
            int row = rowBase + rr;
            float partial = 0.f;
            #pragma unroll
            for (int t2 = 0; t2 < 16; ++t2) {
                int h = t2 * 64 + lane;
                partial += Wo[(size_t)row * 1024 + h] * bv[h];
            }
            #pragma unroll
            for (int off = 32; off > 0; off >>= 1)
                partial += __shfl_xor(partial, off, 64);
            if (lane == 0) bfinal[row] = bo[row] + partial;
        }
    } else if (b < 10004) {
        // g0[j] = sum_h bq[h] * Wk[h, j]
        int j = (b - 10000) * 256 + tid;
        float acc = 0.f;
        #pragma unroll 8
        for (int h = 0; h < 1024; ++h) acc += bq[h] * Wk[(size_t)h * 1024 + j];
        g0[j] = acc;
    } else if (b < 10008) {
        // u[j] = sum_h bk[h] * Wq[h, j]
        int j = (b - 10004) * 256 + tid;
        float acc = 0.f;
        #pragma unroll 8
        for (int h = 0; h < 1024; ++h) acc += bk[h] * Wq[(size_t)h * 1024 + j];
        u[j] = acc;
    } else if (b == 10008) {
        float partial = bq[tid] * bk[tid] + bq[tid + 256] * bk[tid + 256]
                      + bq[tid + 512] * bk[tid + 512] + bq[tid + 768] * bk[tid + 768];
        #pragma unroll
        for (int off = 32; off > 0; off >>= 1)
            partial += __shfl_xor(partial, off, 64);
        __shared__ float red[4];
        if ((tid & 63) == 0) red[tid >> 6] = partial;
        __syncthreads();
        if (tid == 0) bqbk[0] = red[0] + red[1] + red[2] + red[3];
    } else {
        int i = (b - 10009) * 1024 + tid * 4;
        *(float4*)(rsum + i) = float4{0.f, 0.f, 0.f, 0.f};
    }
}

// ---------------------------------------------------------------------------
// Proven 128^2 K-loop (R5 codegen).
// ---------------------------------------------------------------------------
__device__ __forceinline__ void gemm_core(
    const unsigned short* __restrict__ Ab,
    const unsigned short* __restrict__ Bb,
    unsigned short* ldsA, unsigned short* ldsB,
    int mBase, int nBase, int lane, int wave, int K, f32x4 (&acc)[4][4])
{
    const int quad = lane >> 4;
    const int l16  = lane & 15;
    const int wr   = wave >> 1;
    const int wc   = wave & 1;

    for (int k0 = 0; k0 < K; k0 += BK) {
        #pragma unroll
        for (int i = 0; i < 4; ++i) {
            int base = (i * 4 + wave) * 64;
            int s    = base + lane;
            int row  = s >> 3;
            int col  = ((s ^ (s >> 3)) & 7) * 8;
            __builtin_amdgcn_global_load_lds(
                (const __attribute__((address_space(1))) void*)(Ab + (size_t)(mBase + row) * K + (size_t)(k0 + col)),
                (__attribute__((address_space(3))) void*)(&ldsA[base * 8]),
                16, 0, 0);
        }
        #pragma unroll
        for (int i = 0; i < 4; ++i) {
            int base = (i * 4 + wave) * 64;
            int s    = base + lane;
            int row  = s >> 3;
            int col  = ((s ^ (s >> 3)) & 7) * 8;
            __builtin_amdgcn_global_load_lds(
                (const __attribute__((address_space(1))) void*)(Bb + (size_t)(nBase + row) * K + (size_t)(k0 + col)),
                (__attribute__((address_space(3))) void*)(&ldsB[base * 8]),
                16, 0, 0);
        }
        __syncthreads();

        #pragma unroll
        for (int kk = 0; kk < 2; ++kk) {
            bf16x8 af[4], bfv[4];
            #pragma unroll
            for (int mi = 0; mi < 4; ++mi) {
                int r = wr * 64 + mi * 16 + l16;
                int c = kk * 4 + quad;
                af[mi] = *(const bf16x8*)(&ldsA[r * BK + (((c ^ r) & 7) << 3)]);
            }
            #pragma unroll
            for (int ni = 0; ni < 4; ++ni) {
                int r = wc * 64 + ni * 16 + l16;
                int c = kk * 4 + quad;
                bfv[ni] = *(const bf16x8*)(&ldsB[r * BK + (((c ^ r) & 7) << 3)]);
            }
            #pragma unroll
            for (int mi = 0; mi < 4; ++mi)
                #pragma unroll
                for (int ni = 0; ni < 4; ++ni)
                    acc[mi][ni] = __builtin_amdgcn_mfma_f32_16x16x32_bf16(
                        af[mi], bfv[ni], acc[mi][ni], 0, 0, 0);
        }
        __syncthreads();
    }
}

// ---------------------------------------------------------------------------
// Small dispatch: Gt = WkT.(WqT)^T  (i.e. G^T, so qg = x.Gt^T), F = Wo.(WvT)^T,
// and rowadd[s] = x_s . u + bq.bk  (row-offset of scores; 0 for zero biases).
// 256 blocks: [0,64) Gt, [64,128) F, [128,256) rowadd (64 rows each).
// ---------------------------------------------------------------------------
__global__ __launch_bounds__(256) void gemm_gf(
    const unsigned short* __restrict__ w16,
    const unsigned short* __restrict__ x16,
    unsigned short* __restrict__ Gt16, unsigned short* __restrict__ F16,
    const float* __restrict__ u, const float* __restrict__ bqbk,
    float* __restrict__ rowadd)
{
    const int l = blockIdx.x, tid = threadIdx.x;
    if (l < 128) {
        __shared__ unsigned short ldsA[BM * BK];
        __shared__ unsigned short ldsB[BN * BK];
        const unsigned short *Ab, *Bb;
        unsigned short* Cb;
        int f;
        if (l < 64) { f = l;      Ab = w16 + (size_t)1 * 1048576; Bb = w16;                        Cb = Gt16; }
        else        { f = l - 64; Ab = w16 + (size_t)2 * 1048576; Bb = w16 + (size_t)3 * 1048576; Cb = F16;  }
        int mBase = (f >> 3) * BM, nBase = (f & 7) * BN;

        const int lane = tid & 63, wave = tid >> 6;
        const int quad = lane >> 4, l16 = lane & 15;
        const int wr = wave >> 1, wc = wave & 1;

        f32x4 acc[4][4] = {};
        gemm_core(Ab, Bb, ldsA, ldsB, mBase, nBase, lane, wave, 1024, acc);

        #pragma unroll
        for (int mi = 0; mi < 4; ++mi)
            #pragma unroll
            for (int ni = 0; ni < 4; ++ni) {
                int col = nBase + wc * 64 + ni * 16 + l16;
                #pragma unroll
                for (int r = 0; r < 4; ++r) {
                    int row = mBase + wr * 64 + mi * 16 + quad * 4 + r;
                    Cb[(size_t)row * 1024 + col] = f32_to_bf16_rne(acc[mi][ni][r]);
                }
            }
    } else {
        int rb = l - 128;
        int lane = tid & 63, w = tid >> 6;
        float bb0 = bqbk[0];
        for (int rr = 0; rr < 16; ++rr) {
            int row = rb * 64 + w * 16 + rr;
            float partial = 0.f;
            #pragma unroll
            for (int t2 = 0; t2 < 16; ++t2) {
                int h = t2 * 64 + lane;
                partial += bf16_to_f32(x16[(size_t)row * 1024 + h]) * u[h];
            }
            #pragma unroll
            for (int off = 32; off > 0; off >>= 1)
                partial += __shfl_xor(partial, off, 64);
            if (lane == 0) rowadd[row] = partial + bb0;
        }
    }
}

// ---------------------------------------------------------------------------
// qg = x.Gt^T + g0 (512 tiles) and Vot[b] = F.x_b^T (512 tiles), merged.
// 1024 blocks, XCD-contiguous.
// ---------------------------------------------------------------------------
__global__ __launch_bounds__(256) void gemm_qgv(
    const unsigned short* __restrict__ x16,
    const unsigned short* __restrict__ Gt16,
    const unsigned short* __restrict__ F16,
    const float* __restrict__ g0,
    unsigned short* __restrict__ qg16,
    unsigned short* __restrict__ vot16)
{
    __shared__ unsigned short ldsA[BM * BK];
    __shared__ unsigned short ldsB[BN * BK];

    int l   = blockIdx.x;                 // 1024 = 8 * 128
    int idx = (l & 7) * 128 + (l >> 3);   // XCD-contiguous

    const unsigned short *Ab, *Bb;
    unsigned short* Cb;
    const float* bias;
    int mBase, nBase, Cstride;
    if (idx < 512) {
        // qg: M=8192 (both batches), N=1024, K=1024
        mBase = (idx >> 3) * BM; nBase = (idx & 7) * BN;
        Ab = x16; Bb = Gt16; Cb = qg16; bias = g0; Cstride = 1024;
    } else {
        // Vot[b]: M=1024, N=4096, K=1024
        int v = idx - 512;
        int zb = v >> 8, t2 = v & 255;
        mBase = (t2 >> 5) * BM; nBase = (t2 & 31) * BN;
        Ab = F16; Bb = x16 + (size_t)zb * 4096 * 1024;
        Cb = vot16 + (size_t)zb * 1024 * 4096; bias = nullptr; Cstride = 4096;
    }

    const int tid  = threadIdx.x;
    const int lane = tid & 63;
    const int wave = tid >> 6;
    const int quad = lane >> 4;
    const int l16  = lane & 15;
    const int wr   = wave >> 1;
    const int wc   = wave & 1;

    f32x4 acc[4][4] = {};
    gemm_core(Ab, Bb, ldsA, ldsB, mBase, nBase, lane, wave, 1024, acc);

    #pragma unroll
    for (int mi = 0; mi < 4; ++mi)
        #pragma unroll
        for (int ni = 0; ni < 4; ++ni) {
            int col = nBase + wc * 64 + ni * 16 + l16;
            float b = bias ? bias[col] : 0.f;
            #pragma unroll
            for (int r = 0; r < 4; ++r) {
                int row = mBase + wr * 64 + mi * 16 + quad * 4 + r;
                Cb[(size_t)row * Cstride + col] = f32_to_bf16_rne(acc[mi][ni][r] + b);
            }
        }
}

// ---------------------------------------------------------------------------
// scores: z-batched A.Bt^T, 128^2 proven path. MODE 3 only:
// C bf16 = exp((acc + rowadd[row]) * alpha), atomic fp32 rowsums.
// b0 = rowadd (per-GLOBAL-row offset; zero for zero biases).
// ---------------------------------------------------------------------------
template <int MODE>
__global__ __launch_bounds__(256) void gemm_bt(
    const unsigned short* __restrict__ A,
    const unsigned short* __restrict__ Bt,
    void* __restrict__ C,
    const float* __restrict__ b0, float* __restrict__ rowsum,
    float alpha, int M, int N, int K,
    long long aZ, long long bZ, long long cZ)
{
    __shared__ unsigned short ldsA[BM * BK];
    __shared__ unsigned short ldsB[BN * BK];

    const int NB = gridDim.x, MBt = gridDim.y;
    int l  = blockIdx.x + gridDim.x * (blockIdx.y + gridDim.y * blockIdx.z);
    int xcd = l & 7;
    int t   = l >> 3;
    int MBX = MBt >> 1;
    int NBX = NB >> 2;
    int mbl = t % MBX;
    int r1  = t / MBX;
    int nbi = r1 % NBX;
    int zb  = r1 / NBX;
    int mb  = (xcd >> 2) * MBX + mbl;
    int nb  = (xcd & 3) * NBX + nbi;

    const unsigned short* Ab = A  + (size_t)zb * aZ;
    const unsigned short* Bb = Bt + (size_t)zb * bZ;

    const int tid  = threadIdx.x;
    const int lane = tid & 63;
    const int wave = tid >> 6;
    const int quad = lane >> 4;
    const int l16  = lane & 15;
    const int wr   = wave >> 1;
    const int wc   = wave & 1;
    const int mBase = mb * BM;
    const int nBase = nb * BN;

    f32x4 acc[4][4] = {};
    gemm_core(Ab, Bb, ldsA, ldsB, mBase, nBase, lane, wave, K, acc);

    if (MODE == 3) {
        unsigned short* Pz = (unsigned short*)C + (size_t)zb * cZ;
        float* rs = rowsum + (size_t)zb * M;
        const float* raz = b0 + (size_t)zb * M;
        #pragma unroll
        for (int mi = 0; mi < 4; ++mi) {
            #pragma unroll
            for (int r = 0; r < 4; ++r) {
                int row = mBase + wr * 64 + mi * 16 + quad * 4 + r;
                float ra = raz[row];
                float e[4];
                float partial = 0.f;
                #pragma unroll
                for (int ni = 0; ni < 4; ++ni) {
                    e[ni] = __expf((acc[mi][ni][r] + ra) * alpha);
                    partial += e[ni];
                }
                #pragma unroll
                for (int ni = 0; ni < 4; ++ni) {
                    int col = nBase + wc * 64 + ni * 16 + l16;
                    Pz[(size_t)row * N + col] = f32_to_bf16_rne(e[ni]);
                }
                #pragma unroll
                for (int off = 1; off < 16; off <<= 1)
                    partial += __shfl_xor(partial, off, 64);
                if (l16 == 0) atomicAdd(&rs[row], partial);
            }
        }
    }
}

// ---------------------------------------------------------------------------
// final: phase-split GEMM (unchanged from R10). 8 waves (2m x 4n), BK=64,
// double-buffered xor-swizzled LDS, global_load_lds(16B), counted vmcnt once
// per K-tile. Phase = {ds_read + stage issue + [vmcnt] -> s_barrier ->
// lgkmcnt(0)+sched_barrier(0) -> setprio(1) 16xMFMA setprio(0) -> s_barrier}.
// MODE 6: C fp32 = acc/rowsum + b0.
// ---------------------------------------------------------------------------
template <int MODE, int BMt, int BNt>
__global__ __launch_bounds__(512) void gemm8p(
    const unsigned short* __restrict__ A,
    const unsigned short* __restrict__ Bt,
    void* __restrict__ C,
    const float* __restrict__ b0, float* __restrict__ rowsum,
    float alpha, int M, int N, int K,
    long long aZ, long long bZ, long long cZ,
    int MBt, int NB)
{
    constexpr int RW  = BMt / 2;
    constexpr int CW  = BNt / 4;
    constexpr int MI  = RW / 16;
    constexpr int NI  = CW / 16;
    constexpr int NPH = MI / 2;
    constexpr int BL  = (BNt * 64 / 512) / 8;
    constexpr int NWT = BL + NPH - 1;

    __shared__ __align__(16) unsigned short ldsA[2][BMt * 64];
    __shared__ __align__(16) unsigned short ldsB[2][BNt * 64];

    const int l   = blockIdx.x;
    const int xcd = l & 7;
    const int t   = l >> 3;
    const int MBX = MBt >> 1;
    const int NBX = NB >> 2;
    const int mbl = t % MBX;
    const int r1  = t / MBX;
    const int nbi = r1 % NBX;
    const int zb  = r1 / NBX;
    const int mb  = (xcd >> 2) * MBX + mbl;
    const int nb  = (xcd & 3) * NBX + nbi;

    const unsigned short* Ab = A  + (size_t)zb * aZ;
    const unsigned short* Bb = Bt + (size_t)zb * bZ;

    const int tid  = threadIdx.x;
    const int lane = tid & 63;
    const int wave = tid >> 6;
    const int quad = lane >> 4;
    const int l16  = lane & 15;
    const int wr   = wave >> 2;
    const int wc   = wave & 3;
    const int mBase = mb * BMt;
    const int nBase = nb * BNt;
    const int NT    = K >> 6;

    const int aRow0 = ((wave & 4) ? RW : 0) + (wave & 3) * 8;

    auto stageA = [&](int p, int kt, int q) {
        const int rowbase = aRow0 + q * 32;
        const int row = rowbase + (lane >> 3);
        const int col = (((lane & 7) ^ row) & 7) << 3;
        __builtin_amdgcn_global_load_lds(
            (const __attribute__((address_space(1))) void*)(
                Ab + (size_t)(mBase + row) * K + (size_t)((kt << 6) + col)),
            (__attribute__((address_space(3))) void*)(&ldsA[p][rowbase * 64]),
            16, 0, 0);
    };
    auto stageB = [&](int p, int kt) {
        #pragma unroll
        for (int i = 0; i < BL; ++i) {
            const int g   = wave * BL + i;
            const int row = (g << 3) + (lane >> 3);
            const int col = (((lane & 7) ^ row) & 7) << 3;
            __builtin_amdgcn_global_load_lds(
                (const __attribute__((address_space(1))) void*)(
                    Bb + (size_t)(nBase + row) * K + (size_t)((kt << 6) + col)),
                (__attribute__((address_space(3))) void*)(&ldsB[p][g << 9]),
                16, 0, 0);
        }
    };

    bf16x8 bf[NI][2];
    bf16x8 af[2][2];
    auto ldB = [&](int p) {
        #pragma unroll
        for (int n2 = 0; n2 < NI; ++n2)
            #pragma unroll
            for (int kk = 0; kk < 2; ++kk) {
                const int r = wc * CW + n2 * 16 + l16;
                const int c = kk * 4 + quad;
                bf[n2][kk] = *(const bf16x8*)&ldsB[p][r * 64 + (((c ^ r) & 7) << 3)];
            }
    };
    auto ldA = [&](int p, int q) {
        #pragma unroll
        for (int m2 = 0; m2 < 2; ++m2)
            #pragma unroll
            for (int kk = 0; kk < 2; ++kk) {
                const int r = wr * RW + (q * 2 + m2) * 16 + l16;
                const int c = kk * 4 + quad;
                af[m2][kk] = *(const bf16x8*)&ldsA[p][r * 64 + (((c ^ r) & 7) << 3)];
            }
    };

    f32x4 acc[MI][NI] = {};

    stageB(0, 0);
    #pragma unroll
    for (int q = 0; q < NPH; ++q) stageA(0, 0, q);
    if (NT > 1) {
        stageB(1, 1);
        #pragma unroll
        for (int q = 0; q < NPH - 1; ++q) stageA(1, 1, q);
        asm volatile("s_waitcnt vmcnt(%0)" :: "n"(NWT) : "memory");
    } else {
        asm volatile("s_waitcnt vmcnt(0)" ::: "memory");
    }
    __builtin_amdgcn_s_barrier();

    for (int kt = 0; kt < NT; ++kt) {
        const int p = kt & 1;
        #pragma unroll
        for (int q = 0; q < NPH; ++q) {
            if (q == 0) ldB(p);
            ldA(p, q);
            if (q == 0) {
                if (kt + 1 < NT) stageA(p ^ 1, kt + 1, NPH - 1);
            } else if (q == 1) {
                if (kt + 2 < NT) { stageB(p, kt + 2); stageA(p, kt + 2, 0); }
            } else {
                if (kt + 2 < NT) stageA(p, kt + 2, q - 1);
            }
            if (q == NPH - 1) {
                if (kt + 2 < NT) {
                    asm volatile("s_waitcnt vmcnt(%0)" :: "n"(NWT) : "memory");
                } else if (kt + 1 < NT) {
                    asm volatile("s_waitcnt vmcnt(0)" ::: "memory");
                }
            }
            __builtin_amdgcn_s_barrier();
            asm volatile("s_waitcnt lgkmcnt(0)" ::: "memory");
            __builtin_amdgcn_sched_barrier(0);
            __builtin_amdgcn_s_setprio(1);
            #pragma unroll
            for (int m2 = 0; m2 < 2; ++m2)
                #pragma unroll
                for (int n2 = 0; n2 < NI; ++n2)
                    #pragma unroll
                    for (int kk = 0; kk < 2; ++kk)
                        acc[q * 2 + m2][n2] = __builtin_amdgcn_mfma_f32_16x16x32_bf16(
                            af[m2][kk], bf[n2][kk], acc[q * 2 + m2][n2], 0, 0, 0);
            __builtin_amdgcn_s_setprio(0);
            __builtin_amdgcn_s_barrier();
        }
    }

    {
        float* Cz = (float*)C + (size_t)zb * cZ;
        const float* rs = rowsum + (size_t)zb * M;
        #pragma unroll
        for (int mi = 0; mi < MI; ++mi) {
            #pragma unroll
            for (int r = 0; r < 4; ++r) {
                const int row = mBase + wr * RW + mi * 16 + quad * 4 + r;
                const float inv = 1.f / rs[row];
                #pragma unroll
                for (int ni = 0; ni < NI; ++ni) {
                    const int col = nBase + wc * CW + ni * 16 + l16;
                    Cz[(size_t)row * N + col] = acc[mi][ni][r] * inv + b0[col];
                }
            }
        }
    }
}

// ---------------------------------------------------------------------------
extern "C" void kernel_launch(void* const* d_in, const int* in_sizes, int n_in,
                              void* d_out, int out_size, void* d_ws, size_t ws_size,
                              hipStream_t stream)
{
    const float* x  = (const float*)d_in[0];
    const float* Wq = (const float*)d_in[1];
    const float* bq = (const float*)d_in[2];
    const float* Wk = (const float*)d_in[3];
    const float* bk = (const float*)d_in[4];
    const float* Wv = (const float*)d_in[5];
    const float* bv = (const float*)d_in[6];
    const float* Wo = (const float*)d_in[7];
    const float* bo = (const float*)d_in[8];
    float* out = (float*)d_out;

    const int S = 4096, H = 1024, Bsz = 2;
    const int M = Bsz * S;   // 8192

    char* p = (char*)d_ws;
    auto alloc = [&](size_t bytes) -> char* {
        char* r = p; p += (bytes + 255) & ~(size_t)255; return r;
    };
    // footprint ~130 MiB (ws >= 153 MiB proven in R2)
    unsigned short* w16   = (unsigned short*)alloc((size_t)4 * H * H * 2);  // WqT|WkT|Wo|WvT
    unsigned short* F16   = (unsigned short*)alloc((size_t)H * H * 2);
    unsigned short* Gt16  = (unsigned short*)alloc((size_t)H * H * 2);
    unsigned short* qg16  = (unsigned short*)alloc((size_t)M * H * 2);
    unsigned short* vot16 = (unsigned short*)alloc((size_t)Bsz * H * S * 2); // [B][H][S]
    unsigned short* x16   = (unsigned short*)alloc((size_t)M * H * 2);
    float*          rsum  = (float*)alloc((size_t)M * 4);
    float*          bfin  = (float*)alloc((size_t)H * 4);
    float*          g0    = (float*)alloc((size_t)H * 4);
    float*          uvec  = (float*)alloc((size_t)H * 4);
    float*          bqbk  = (float*)alloc(256);
    float*          rowadd= (float*)alloc((size_t)M * 4);
    unsigned short* p16   = (unsigned short*)alloc((size_t)Bsz * S * S * 2);

    // 1) converts + transposes + bfinal + g0/u/bqbk + rowsum zeroing
    cvt_all<<<10017, 256, 0, stream>>>(x, Wq, Wk, Wo, Wv, bq, bk, bv, bo,
                                       x16, w16, rsum, bfin, g0, uvec, bqbk);

    // 2) Gt = G^T = WkT.WqT^T, F = Wo.WvT^T, rowadd = x.u + bq.bk
    gemm_gf<<<256, 256, 0, stream>>>(w16, x16, Gt16, F16, uvec, bqbk, rowadd);

    // 3) qg = x.Gt^T + g0  and  Vot[b] = F.x_b^T
    gemm_qgv<<<1024, 256, 0, stream>>>(x16, Gt16, F16, g0, qg16, vot16);

    // 4) P_un[b] = exp((qg.x_b^T + rowadd)/8) + atomic rowsums
    gemm_bt<3><<<dim3(S / BN, S / BM, 2), 256, 0, stream>>>(
        qg16, x16, p16, rowadd, rsum, 0.125f, S, S, 1024,
        (long long)S * H, (long long)S * H, (long long)S * S);

    // 5) out[b] = (P_un . Vot^T)/rowsum + bfinal   (128x256 phase-split)
    gemm8p<6, 128, 256><<<256, 512, 0, stream>>>(
        p16, vot16, out, bfin, rsum, 1.f, S, H, 4096,
        (long long)S * S, (long long)H * S, (long long)S * H, 32, 4);
}

// Round 4
// 378.094 us; speedup vs baseline: 1.0199x; 1.0199x over previous
//
#include <hip/hip_runtime.h>
#include <stdint.h>

// ---------------------------------------------------------------------------
// DistributedAttention on MI355X (gfx950)
//   q = x Wq^T + bq ; k = x Wk^T + bk ; v = x Wv^T + bv
//   P = softmax(q k^T / 8) ; out = P v Wo^T + bo
// Factorizations:
//   F  = Wo . Wv                 (2.1 GF, replaces the 17.2 GF v-proj)   [R7]
//   Vot= F . x^T per batch       ([H][S] bf16)                           [R7]
//   G  = Wq^T . Wk  (batch-indep, 2.1 GF)                                [R11]
//   qg = x . G + g0, g0 = bq^T Wk (column-varying bias term)             [R11]
//   scores = qg . x^T  (+ per-row constants that CANCEL in softmax)      [R12]
//     R12 insight: the row-constant terms (x.(Wq^T bk) and bq.bk) add a
//     constant to every element of a scores ROW; softmax is row-wise, so
//     exp(c/8) cancels between P and rowsum. rowadd/u/bqbk are deleted —
//     this removes R11's 25 µs latency-bound matvec regression while
//     keeping the 17.2 GF projection elimination.
//   P_un = exp(scores / 8)       (bf16 + atomic fp32 rowsums)
//   out  = (P_un . Vot^T)/rowsum + bfinal,  bfinal = bo + Wo.bv
// R12 dispatches: cvt_all -> gemm_gf (Gt,F; 128 blocks) -> gemm_qgv
//   (qg+Vot, 1024 blocks) -> scores (gemm_bt<3>, epilogue bit-identical to
//   R10) -> final (gemm8p 128x256 phase-split, unchanged).
// ---------------------------------------------------------------------------

typedef __bf16 bf16x8 __attribute__((ext_vector_type(8)));
typedef float  f32x4  __attribute__((ext_vector_type(4)));

__device__ __forceinline__ unsigned short f32_to_bf16_rne(float f) {
    uint32_t u = __builtin_bit_cast(uint32_t, f);
    uint32_t r = (u + 0x7FFFu + ((u >> 16) & 1u)) >> 16;
    return (unsigned short)r;
}

#define BM 128
#define BN 128
#define BK 64

// ---------------------------------------------------------------------------
// One-dispatch prep, 10012 blocks:
//   [0,8192)        x fp32 -> x16 bf16
//   [8192,9216)     Wo straight convert -> w16 slot 2
//   [9216,9984)     WqT, WkT, WvT 64x64-tile transposes -> slots 0,1,3
//   [9984,10000)    bfinal = bo + Wo.bv
//   [10000,10004)   g0 = bq^T Wk   (per-col dot, coalesced over j)
//   [10004,10012)   zero rsum
// ---------------------------------------------------------------------------
__global__ __launch_bounds__(256) void cvt_all(
    const float* __restrict__ x,
    const float* __restrict__ Wq, const float* __restrict__ Wk,
    const float* __restrict__ Wo, const float* __restrict__ Wv,
    const float* __restrict__ bq,
    const float* __restrict__ bv, const float* __restrict__ bo,
    unsigned short* __restrict__ x16, unsigned short* __restrict__ w16,
    float* __restrict__ rsum, float* __restrict__ bfinal,
    float* __restrict__ g0)
{
    const int b = blockIdx.x, tid = threadIdx.x;
    if (b < 8192) {
        int i = (b * 256 + tid) * 4;
        float4 v = *(const float4*)(x + i);
        ushort4 o;
        o.x = f32_to_bf16_rne(v.x); o.y = f32_to_bf16_rne(v.y);
        o.z = f32_to_bf16_rne(v.z); o.w = f32_to_bf16_rne(v.w);
        *(ushort4*)(x16 + i) = o;
    } else if (b < 9216) {
        int i = ((b - 8192) * 256 + tid) * 4;
        float4 v = *(const float4*)(Wo + i);
        ushort4 o;
        o.x = f32_to_bf16_rne(v.x); o.y = f32_to_bf16_rne(v.y);
        o.z = f32_to_bf16_rne(v.z); o.w = f32_to_bf16_rne(v.w);
        *(ushort4*)(w16 + (size_t)2 * 1048576 + i) = o;
    } else if (b < 9984) {
        // transpose one 64x64 tile of {Wq,Wk,Wv} into w16 slot {0,1,3}
        __shared__ unsigned short tl[64 * 68];   // [c][r], stride 68
        int t = b - 9216;
        int which = t >> 8;                      // 0:Wq 1:Wk 2:Wv
        const float* src = which == 0 ? Wq : which == 1 ? Wk : Wv;
        size_t slot = which == 0 ? 0 : which == 1 ? 1 : 3;
        int tile = t & 255, tr = tile >> 4, tc = tile & 15;
        #pragma unroll
        for (int it = 0; it < 4; ++it) {
            int r  = it * 16 + (tid >> 4);
            int c0 = (tid & 15) * 4;
            float4 v = *(const float4*)(src + (size_t)(tr * 64 + r) * 1024 + tc * 64 + c0);
            tl[(c0 + 0) * 68 + r] = f32_to_bf16_rne(v.x);
            tl[(c0 + 1) * 68 + r] = f32_to_bf16_rne(v.y);
            tl[(c0 + 2) * 68 + r] = f32_to_bf16_rne(v.z);
            tl[(c0 + 3) * 68 + r] = f32_to_bf16_rne(v.w);
        }
        __syncthreads();
        #pragma unroll
        for (int it = 0; it < 4; ++it) {
            int c  = it * 16 + (tid >> 4);
            int r0 = (tid & 15) * 4;
            ushort4 o;
            o.x = tl[c * 68 + r0 + 0]; o.y = tl[c * 68 + r0 + 1];
            o.z = tl[c * 68 + r0 + 2]; o.w = tl[c * 68 + r0 + 3];
            *(ushort4*)(w16 + slot * 1048576 + (size_t)(tc * 64 + c) * 1024 + tr * 64 + r0) = o;
        }
    } else if (b < 10000) {
        // bfinal[row] = bo[row] + dot(Wo[row,:], bv)
        int bb = b - 9984;
        int lane = tid & 63, wv_ = tid >> 6;
        int rowBase = bb * 64 + wv_ * 16;
        for (int rr = 0; rr < 16; ++rr) {
            int row = rowBase + rr;
            float partial = 0.f;
            #pragma unroll
            for (int t2 = 0; t2 < 16; ++t2) {
                int h = t2 * 64 + lane;
                partial += Wo[(size_t)row * 1024 + h] * bv[h];
            }
            #pragma unroll
            for (int off = 32; off > 0; off >>= 1)
                partial += __shfl_xor(partial, off, 64);
            if (lane == 0) bfinal[row] = bo[row] + partial;
        }
    } else if (b < 10004) {
        // g0[j] = sum_o bq[o] * Wk[o, j]
        int j = (b - 10000) * 256 + tid;
        float acc = 0.f;
        #pragma unroll 8
        for (int h = 0; h < 1024; ++h) acc += bq[h] * Wk[(size_t)h * 1024 + j];
        g0[j] = acc;
    } else {
        int i = (b - 10004) * 1024 + tid * 4;
        *(float4*)(rsum + i) = float4{0.f, 0.f, 0.f, 0.f};
    }
}

// ---------------------------------------------------------------------------
// Proven 128^2 K-loop (R5 codegen).
// ---------------------------------------------------------------------------
__device__ __forceinline__ void gemm_core(
    const unsigned short* __restrict__ Ab,
    const unsigned short* __restrict__ Bb,
    unsigned short* ldsA, unsigned short* ldsB,
    int mBase, int nBase, int lane, int wave, int K, f32x4 (&acc)[4][4])
{
    const int quad = lane >> 4;
    const int l16  = lane & 15;
    const int wr   = wave >> 1;
    const int wc   = wave & 1;

    for (int k0 = 0; k0 < K; k0 += BK) {
        #pragma unroll
        for (int i = 0; i < 4; ++i) {
            int base = (i * 4 + wave) * 64;
            int s    = base + lane;
            int row  = s >> 3;
            int col  = ((s ^ (s >> 3)) & 7) * 8;
            __builtin_amdgcn_global_load_lds(
                (const __attribute__((address_space(1))) void*)(Ab + (size_t)(mBase + row) * K + (size_t)(k0 + col)),
                (__attribute__((address_space(3))) void*)(&ldsA[base * 8]),
                16, 0, 0);
        }
        #pragma unroll
        for (int i = 0; i < 4; ++i) {
            int base = (i * 4 + wave) * 64;
            int s    = base + lane;
            int row  = s >> 3;
            int col  = ((s ^ (s >> 3)) & 7) * 8;
            __builtin_amdgcn_global_load_lds(
                (const __attribute__((address_space(1))) void*)(Bb + (size_t)(nBase + row) * K + (size_t)(k0 + col)),
                (__attribute__((address_space(3))) void*)(&ldsB[base * 8]),
                16, 0, 0);
        }
        __syncthreads();

        #pragma unroll
        for (int kk = 0; kk < 2; ++kk) {
            bf16x8 af[4], bfv[4];
            #pragma unroll
            for (int mi = 0; mi < 4; ++mi) {
                int r = wr * 64 + mi * 16 + l16;
                int c = kk * 4 + quad;
                af[mi] = *(const bf16x8*)(&ldsA[r * BK + (((c ^ r) & 7) << 3)]);
            }
            #pragma unroll
            for (int ni = 0; ni < 4; ++ni) {
                int r = wc * 64 + ni * 16 + l16;
                int c = kk * 4 + quad;
                bfv[ni] = *(const bf16x8*)(&ldsB[r * BK + (((c ^ r) & 7) << 3)]);
            }
            #pragma unroll
            for (int mi = 0; mi < 4; ++mi)
                #pragma unroll
                for (int ni = 0; ni < 4; ++ni)
                    acc[mi][ni] = __builtin_amdgcn_mfma_f32_16x16x32_bf16(
                        af[mi], bfv[ni], acc[mi][ni], 0, 0, 0);
        }
        __syncthreads();
    }
}

// ---------------------------------------------------------------------------
// Small dispatch (128 blocks): Gt = WkT.(WqT)^T (i.e. G^T, so qg = x.Gt^T)
// and F = Wo.(WvT)^T.  Pure GEMM — the R11 rowadd half is deleted (it
// cancels in softmax).
// ---------------------------------------------------------------------------
__global__ __launch_bounds__(256) void gemm_gf(
    const unsigned short* __restrict__ w16,
    unsigned short* __restrict__ Gt16, unsigned short* __restrict__ F16)
{
    __shared__ unsigned short ldsA[BM * BK];
    __shared__ unsigned short ldsB[BN * BK];

    const int l = blockIdx.x, tid = threadIdx.x;
    const unsigned short *Ab, *Bb;
    unsigned short* Cb;
    int f;
    if (l < 64) { f = l;      Ab = w16 + (size_t)1 * 1048576; Bb = w16;                        Cb = Gt16; }
    else        { f = l - 64; Ab = w16 + (size_t)2 * 1048576; Bb = w16 + (size_t)3 * 1048576; Cb = F16;  }
    int mBase = (f >> 3) * BM, nBase = (f & 7) * BN;

    const int lane = tid & 63, wave = tid >> 6;
    const int quad = lane >> 4, l16 = lane & 15;
    const int wr = wave >> 1, wc = wave & 1;

    f32x4 acc[4][4] = {};
    gemm_core(Ab, Bb, ldsA, ldsB, mBase, nBase, lane, wave, 1024, acc);

    #pragma unroll
    for (int mi = 0; mi < 4; ++mi)
        #pragma unroll
        for (int ni = 0; ni < 4; ++ni) {
            int col = nBase + wc * 64 + ni * 16 + l16;
            #pragma unroll
            for (int r = 0; r < 4; ++r) {
                int row = mBase + wr * 64 + mi * 16 + quad * 4 + r;
                Cb[(size_t)row * 1024 + col] = f32_to_bf16_rne(acc[mi][ni][r]);
            }
        }
}

// ---------------------------------------------------------------------------
// qg = x.Gt^T + g0 (512 tiles) and Vot[b] = F.x_b^T (512 tiles), merged.
// 1024 blocks, XCD-contiguous.
// ---------------------------------------------------------------------------
__global__ __launch_bounds__(256) void gemm_qgv(
    const unsigned short* __restrict__ x16,
    const unsigned short* __restrict__ Gt16,
    const unsigned short* __restrict__ F16,
    const float* __restrict__ g0,
    unsigned short* __restrict__ qg16,
    unsigned short* __restrict__ vot16)
{
    __shared__ unsigned short ldsA[BM * BK];
    __shared__ unsigned short ldsB[BN * BK];

    int l   = blockIdx.x;                 // 1024 = 8 * 128
    int idx = (l & 7) * 128 + (l >> 3);   // XCD-contiguous

    const unsigned short *Ab, *Bb;
    unsigned short* Cb;
    const float* bias;
    int mBase, nBase, Cstride;
    if (idx < 512) {
        // qg: M=8192 (both batches), N=1024, K=1024
        mBase = (idx >> 3) * BM; nBase = (idx & 7) * BN;
        Ab = x16; Bb = Gt16; Cb = qg16; bias = g0; Cstride = 1024;
    } else {
        // Vot[b]: M=1024, N=4096, K=1024
        int v = idx - 512;
        int zb = v >> 8, t2 = v & 255;
        mBase = (t2 >> 5) * BM; nBase = (t2 & 31) * BN;
        Ab = F16; Bb = x16 + (size_t)zb * 4096 * 1024;
        Cb = vot16 + (size_t)zb * 1024 * 4096; bias = nullptr; Cstride = 4096;
    }

    const int tid  = threadIdx.x;
    const int lane = tid & 63;
    const int wave = tid >> 6;
    const int quad = lane >> 4;
    const int l16  = lane & 15;
    const int wr   = wave >> 1;
    const int wc   = wave & 1;

    f32x4 acc[4][4] = {};
    gemm_core(Ab, Bb, ldsA, ldsB, mBase, nBase, lane, wave, 1024, acc);

    #pragma unroll
    for (int mi = 0; mi < 4; ++mi)
        #pragma unroll
        for (int ni = 0; ni < 4; ++ni) {
            int col = nBase + wc * 64 + ni * 16 + l16;
            float b = bias ? bias[col] : 0.f;
            #pragma unroll
            for (int r = 0; r < 4; ++r) {
                int row = mBase + wr * 64 + mi * 16 + quad * 4 + r;
                Cb[(size_t)row * Cstride + col] = f32_to_bf16_rne(acc[mi][ni][r] + b);
            }
        }
}

// ---------------------------------------------------------------------------
// scores: z-batched A.Bt^T, 128^2 proven path. MODE 3:
// C bf16 = exp(acc * alpha), atomic fp32 rowsums. (Epilogue bit-identical
// to R10 — row-constant bias terms cancel in softmax.)
// ---------------------------------------------------------------------------
template <int MODE>
__global__ __launch_bounds__(256) void gemm_bt(
    const unsigned short* __restrict__ A,
    const unsigned short* __restrict__ Bt,
    void* __restrict__ C,
    const float* __restrict__ b0, float* __restrict__ rowsum,
    float alpha, int M, int N, int K,
    long long aZ, long long bZ, long long cZ)
{
    __shared__ unsigned short ldsA[BM * BK];
    __shared__ unsigned short ldsB[BN * BK];

    const int NB = gridDim.x, MBt = gridDim.y;
    int l  = blockIdx.x + gridDim.x * (blockIdx.y + gridDim.y * blockIdx.z);
    int xcd = l & 7;
    int t   = l >> 3;
    int MBX = MBt >> 1;
    int NBX = NB >> 2;
    int mbl = t % MBX;
    int r1  = t / MBX;
    int nbi = r1 % NBX;
    int zb  = r1 / NBX;
    int mb  = (xcd >> 2) * MBX + mbl;
    int nb  = (xcd & 3) * NBX + nbi;

    const unsigned short* Ab = A  + (size_t)zb * aZ;
    const unsigned short* Bb = Bt + (size_t)zb * bZ;

    const int tid  = threadIdx.x;
    const int lane = tid & 63;
    const int wave = tid >> 6;
    const int quad = lane >> 4;
    const int l16  = lane & 15;
    const int wr   = wave >> 1;
    const int wc   = wave & 1;
    const int mBase = mb * BM;
    const int nBase = nb * BN;

    f32x4 acc[4][4] = {};
    gemm_core(Ab, Bb, ldsA, ldsB, mBase, nBase, lane, wave, K, acc);

    if (MODE == 3) {
        unsigned short* Pz = (unsigned short*)C + (size_t)zb * cZ;
        float* rs = rowsum + (size_t)zb * M;
        #pragma unroll
        for (int mi = 0; mi < 4; ++mi) {
            #pragma unroll
            for (int r = 0; r < 4; ++r) {
                int row = mBase + wr * 64 + mi * 16 + quad * 4 + r;
                float e[4];
                float partial = 0.f;
                #pragma unroll
                for (int ni = 0; ni < 4; ++ni) {
                    e[ni] = __expf(acc[mi][ni][r] * alpha);
                    partial += e[ni];
                }
                #pragma unroll
                for (int ni = 0; ni < 4; ++ni) {
                    int col = nBase + wc * 64 + ni * 16 + l16;
                    Pz[(size_t)row * N + col] = f32_to_bf16_rne(e[ni]);
                }
                #pragma unroll
                for (int off = 1; off < 16; off <<= 1)
                    partial += __shfl_xor(partial, off, 64);
                if (l16 == 0) atomicAdd(&rs[row], partial);
            }
        }
    }
}

// ---------------------------------------------------------------------------
// final: phase-split GEMM (unchanged from R10). 8 waves (2m x 4n), BK=64,
// double-buffered xor-swizzled LDS, global_load_lds(16B), counted vmcnt once
// per K-tile. Phase = {ds_read + stage issue + [vmcnt] -> s_barrier ->
// lgkmcnt(0)+sched_barrier(0) -> setprio(1) 16xMFMA setprio(0) -> s_barrier}.
// MODE 6: C fp32 = acc/rowsum + b0.
// ---------------------------------------------------------------------------
template <int MODE, int BMt, int BNt>
__global__ __launch_bounds__(512) void gemm8p(
    const unsigned short* __restrict__ A,
    const unsigned short* __restrict__ Bt,
    void* __restrict__ C,
    const float* __restrict__ b0, float* __restrict__ rowsum,
    float alpha, int M, int N, int K,
    long long aZ, long long bZ, long long cZ,
    int MBt, int NB)
{
    constexpr int RW  = BMt / 2;
    constexpr int CW  = BNt / 4;
    constexpr int MI  = RW / 16;
    constexpr int NI  = CW / 16;
    constexpr int NPH = MI / 2;
    constexpr int BL  = (BNt * 64 / 512) / 8;
    constexpr int NWT = BL + NPH - 1;

    __shared__ __align__(16) unsigned short ldsA[2][BMt * 64];
    __shared__ __align__(16) unsigned short ldsB[2][BNt * 64];

    const int l   = blockIdx.x;
    const int xcd = l & 7;
    const int t   = l >> 3;
    const int MBX = MBt >> 1;
    const int NBX = NB >> 2;
    const int mbl = t % MBX;
    const int r1  = t / MBX;
    const int nbi = r1 % NBX;
    const int zb  = r1 / NBX;
    const int mb  = (xcd >> 2) * MBX + mbl;
    const int nb  = (xcd & 3) * NBX + nbi;

    const unsigned short* Ab = A  + (size_t)zb * aZ;
    const unsigned short* Bb = Bt + (size_t)zb * bZ;

    const int tid  = threadIdx.x;
    const int lane = tid & 63;
    const int wave = tid >> 6;
    const int quad = lane >> 4;
    const int l16  = lane & 15;
    const int wr   = wave >> 2;
    const int wc   = wave & 3;
    const int mBase = mb * BMt;
    const int nBase = nb * BNt;
    const int NT    = K >> 6;

    const int aRow0 = ((wave & 4) ? RW : 0) + (wave & 3) * 8;

    auto stageA = [&](int p, int kt, int q) {
        const int rowbase = aRow0 + q * 32;
        const int row = rowbase + (lane >> 3);
        const int col = (((lane & 7) ^ row) & 7) << 3;
        __builtin_amdgcn_global_load_lds(
            (const __attribute__((address_space(1))) void*)(
                Ab + (size_t)(mBase + row) * K + (size_t)((kt << 6) + col)),
            (__attribute__((address_space(3))) void*)(&ldsA[p][rowbase * 64]),
            16, 0, 0);
    };
    auto stageB = [&](int p, int kt) {
        #pragma unroll
        for (int i = 0; i < BL; ++i) {
            const int g   = wave * BL + i;
            const int row = (g << 3) + (lane >> 3);
            const int col = (((lane & 7) ^ row) & 7) << 3;
            __builtin_amdgcn_global_load_lds(
                (const __attribute__((address_space(1))) void*)(
                    Bb + (size_t)(nBase + row) * K + (size_t)((kt << 6) + col)),
                (__attribute__((address_space(3))) void*)(&ldsB[p][g << 9]),
                16, 0, 0);
        }
    };

    bf16x8 bf[NI][2];
    bf16x8 af[2][2];
    auto ldB = [&](int p) {
        #pragma unroll
        for (int n2 = 0; n2 < NI; ++n2)
            #pragma unroll
            for (int kk = 0; kk < 2; ++kk) {
                const int r = wc * CW + n2 * 16 + l16;
                const int c = kk * 4 + quad;
                bf[n2][kk] = *(const bf16x8*)&ldsB[p][r * 64 + (((c ^ r) & 7) << 3)];
            }
    };
    auto ldA = [&](int p, int q) {
        #pragma unroll
        for (int m2 = 0; m2 < 2; ++m2)
            #pragma unroll
            for (int kk = 0; kk < 2; ++kk) {
                const int r = wr * RW + (q * 2 + m2) * 16 + l16;
                const int c = kk * 4 + quad;
                af[m2][kk] = *(const bf16x8*)&ldsA[p][r * 64 + (((c ^ r) & 7) << 3)];
            }
    };

    f32x4 acc[MI][NI] = {};

    stageB(0, 0);
    #pragma unroll
    for (int q = 0; q < NPH; ++q) stageA(0, 0, q);
    if (NT > 1) {
        stageB(1, 1);
        #pragma unroll
        for (int q = 0; q < NPH - 1; ++q) stageA(1, 1, q);
        asm volatile("s_waitcnt vmcnt(%0)" :: "n"(NWT) : "memory");
    } else {
        asm volatile("s_waitcnt vmcnt(0)" ::: "memory");
    }
    __builtin_amdgcn_s_barrier();

    for (int kt = 0; kt < NT; ++kt) {
        const int p = kt & 1;
        #pragma unroll
        for (int q = 0; q < NPH; ++q) {
            if (q == 0) ldB(p);
            ldA(p, q);
            if (q == 0) {
                if (kt + 1 < NT) stageA(p ^ 1, kt + 1, NPH - 1);
            } else if (q == 1) {
                if (kt + 2 < NT) { stageB(p, kt + 2); stageA(p, kt + 2, 0); }
            } else {
                if (kt + 2 < NT) stageA(p, kt + 2, q - 1);
            }
            if (q == NPH - 1) {
                if (kt + 2 < NT) {
                    asm volatile("s_waitcnt vmcnt(%0)" :: "n"(NWT) : "memory");
                } else if (kt + 1 < NT) {
                    asm volatile("s_waitcnt vmcnt(0)" ::: "memory");
                }
            }
            __builtin_amdgcn_s_barrier();
            asm volatile("s_waitcnt lgkmcnt(0)" ::: "memory");
            __builtin_amdgcn_sched_barrier(0);
            __builtin_amdgcn_s_setprio(1);
            #pragma unroll
            for (int m2 = 0; m2 < 2; ++m2)
                #pragma unroll
                for (int n2 = 0; n2 < NI; ++n2)
                    #pragma unroll
                    for (int kk = 0; kk < 2; ++kk)
                        acc[q * 2 + m2][n2] = __builtin_amdgcn_mfma_f32_16x16x32_bf16(
                            af[m2][kk], bf[n2][kk], acc[q * 2 + m2][n2], 0, 0, 0);
            __builtin_amdgcn_s_setprio(0);
            __builtin_amdgcn_s_barrier();
        }
    }

    {
        float* Cz = (float*)C + (size_t)zb * cZ;
        const float* rs = rowsum + (size_t)zb * M;
        #pragma unroll
        for (int mi = 0; mi < MI; ++mi) {
            #pragma unroll
            for (int r = 0; r < 4; ++r) {
                const int row = mBase + wr * RW + mi * 16 + quad * 4 + r;
                const float inv = 1.f / rs[row];
                #pragma unroll
                for (int ni = 0; ni < NI; ++ni) {
                    const int col = nBase + wc * CW + ni * 16 + l16;
                    Cz[(size_t)row * N + col] = acc[mi][ni][r] * inv + b0[col];
                }
            }
        }
    }
}

// ---------------------------------------------------------------------------
extern "C" void kernel_launch(void* const* d_in, const int* in_sizes, int n_in,
                              void* d_out, int out_size, void* d_ws, size_t ws_size,
                              hipStream_t stream)
{
    const float* x  = (const float*)d_in[0];
    const float* Wq = (const float*)d_in[1];
    const float* bq = (const float*)d_in[2];
    const float* Wk = (const float*)d_in[3];
    const float* bv = (const float*)d_in[6];
    const float* Wv = (const float*)d_in[5];
    const float* Wo = (const float*)d_in[7];
    const float* bo = (const float*)d_in[8];
    float* out = (float*)d_out;

    const int S = 4096, H = 1024, Bsz = 2;
    const int M = Bsz * S;   // 8192

    char* p = (char*)d_ws;
    auto alloc = [&](size_t bytes) -> char* {
        char* r = p; p += (bytes + 255) & ~(size_t)255; return r;
    };
    // footprint ~124 MiB (ws >= 153 MiB proven in R2)
    unsigned short* w16   = (unsigned short*)alloc((size_t)4 * H * H * 2);  // WqT|WkT|Wo|WvT
    unsigned short* F16   = (unsigned short*)alloc((size_t)H * H * 2);
    unsigned short* Gt16  = (unsigned short*)alloc((size_t)H * H * 2);
    unsigned short* qg16  = (unsigned short*)alloc((size_t)M * H * 2);
    unsigned short* vot16 = (unsigned short*)alloc((size_t)Bsz * H * S * 2); // [B][H][S]
    unsigned short* x16   = (unsigned short*)alloc((size_t)M * H * 2);
    float*          rsum  = (float*)alloc((size_t)M * 4);
    float*          bfin  = (float*)alloc((size_t)H * 4);
    float*          g0    = (float*)alloc((size_t)H * 4);
    unsigned short* p16   = (unsigned short*)alloc((size_t)Bsz * S * S * 2);

    // 1) converts + transposes + bfinal + g0 + rowsum zeroing
    cvt_all<<<10012, 256, 0, stream>>>(x, Wq, Wk, Wo, Wv, bq, bv, bo,
                                       x16, w16, rsum, bfin, g0);

    // 2) Gt = G^T = WkT.WqT^T, F = Wo.WvT^T
    gemm_gf<<<128, 256, 0, stream>>>(w16, Gt16, F16);

    // 3) qg = x.Gt^T + g0  and  Vot[b] = F.x_b^T
    gemm_qgv<<<1024, 256, 0, stream>>>(x16, Gt16, F16, g0, qg16, vot16);

    // 4) P_un[b] = exp((qg.x_b^T)/8) + atomic rowsums
    //    (row-constant bias terms cancel in softmax; epilogue = R10's)
    gemm_bt<3><<<dim3(S / BN, S / BM, 2), 256, 0, stream>>>(
        qg16, x16, p16, nullptr, rsum, 0.125f, S, S, 1024,
        (long long)S * H, (long long)S * H, (long long)S * S);

    // 5) out[b] = (P_un . Vot^T)/rowsum + bfinal   (128x256 phase-split)
    gemm8p<6, 128, 256><<<256, 512, 0, stream>>>(
        p16, vot16, out, bfin, rsum, 1.f, S, H, 4096,
        (long long)S * S, (long long)H * S, (long long)S * H, 32, 4);
}

// Round 5
// 349.193 us; speedup vs baseline: 1.1043x; 1.0828x over previous
//
#include <hip/hip_runtime.h>
#include <stdint.h>

// ---------------------------------------------------------------------------
// DistributedAttention on MI355X (gfx950)
//   q = x Wq^T + bq ; k = x Wk^T + bk ; v = x Wv^T + bv
//   P = softmax(q k^T / 8) ; out = P v Wo^T + bo
// Factorizations:
//   F  = Wo . Wv                  (2.1 GF, replaces the 17.2 GF v-proj)  [R7]
//   Vot= F . x^T per batch        ([H][S] bf16)                          [R7]
//   G  = Wq^T . Wk  (batch-indep) ; qg = x . G + g0, g0 = bq^T Wk        [R11]
//   scores = qg . x^T   (row-constant terms cancel in softmax)           [R12]
//   P_un = exp(scores / 8)        (bf16 + atomic fp32 rowsums)
//   out  = (P_un . Vot^T)/rowsum + bfinal,  bfinal = bo + Wo.bv
// R13: (1) g0 tail fix — the 4-block strided matvec (~25-48 µs serial tail
//   on 4 CUs at the END of cvt) becomes 64 distributed blocks reading Wk
//   ROWS (coalesced) with atomicAdd partials; g0/rsum zeroed via
//   hipMemsetAsync before cvt (stream-ordered, graph-capturable).
//   (2) scores ported to the R10-corrected 8-phase schedule at 256x256
//   (gemm8p<3,256,256>, 512 blocks = 2 rounds of 1 blk/CU). R9 proved the
//   256^2 numerics (same per-element K order); R10's fence fix removed
//   R9's scheduling pathology (final improved ~95 -> <=89). gemm_bt is
//   now dead and deleted.
// ---------------------------------------------------------------------------

typedef __bf16 bf16x8 __attribute__((ext_vector_type(8)));
typedef float  f32x4  __attribute__((ext_vector_type(4)));

__device__ __forceinline__ unsigned short f32_to_bf16_rne(float f) {
    uint32_t u = __builtin_bit_cast(uint32_t, f);
    uint32_t r = (u + 0x7FFFu + ((u >> 16) & 1u)) >> 16;
    return (unsigned short)r;
}

#define BM 128
#define BN 128
#define BK 64

// ---------------------------------------------------------------------------
// One-dispatch prep, 10064 blocks:
//   [0,8192)        x fp32 -> x16 bf16
//   [8192,9216)     Wo straight convert -> w16 slot 2
//   [9216,9984)     WqT, WkT, WvT 64x64-tile transposes -> slots 0,1,3
//   [9984,10000)    bfinal = bo + Wo.bv
//   [10000,10064)   g0 += bq[h-range]^T Wk[h-range,:]  (64 blocks, each 16
//                   coalesced Wk rows; g0 pre-zeroed by hipMemsetAsync)
// ---------------------------------------------------------------------------
__global__ __launch_bounds__(256) void cvt_all(
    const float* __restrict__ x,
    const float* __restrict__ Wq, const float* __restrict__ Wk,
    const float* __restrict__ Wo, const float* __restrict__ Wv,
    const float* __restrict__ bq,
    const float* __restrict__ bv, const float* __restrict__ bo,
    unsigned short* __restrict__ x16, unsigned short* __restrict__ w16,
    float* __restrict__ bfinal, float* __restrict__ g0)
{
    const int b = blockIdx.x, tid = threadIdx.x;
    if (b < 8192) {
        int i = (b * 256 + tid) * 4;
        float4 v = *(const float4*)(x + i);
        ushort4 o;
        o.x = f32_to_bf16_rne(v.x); o.y = f32_to_bf16_rne(v.y);
        o.z = f32_to_bf16_rne(v.z); o.w = f32_to_bf16_rne(v.w);
        *(ushort4*)(x16 + i) = o;
    } else if (b < 9216) {
        int i = ((b - 8192) * 256 + tid) * 4;
        float4 v = *(const float4*)(Wo + i);
        ushort4 o;
        o.x = f32_to_bf16_rne(v.x); o.y = f32_to_bf16_rne(v.y);
        o.z = f32_to_bf16_rne(v.z); o.w = f32_to_bf16_rne(v.w);
        *(ushort4*)(w16 + (size_t)2 * 1048576 + i) = o;
    } else if (b < 9984) {
        // transpose one 64x64 tile of {Wq,Wk,Wv} into w16 slot {0,1,3}
        __shared__ unsigned short tl[64 * 68];   // [c][r], stride 68
        int t = b - 9216;
        int which = t >> 8;                      // 0:Wq 1:Wk 2:Wv
        const float* src = which == 0 ? Wq : which == 1 ? Wk : Wv;
        size_t slot = which == 0 ? 0 : which == 1 ? 1 : 3;
        int tile = t & 255, tr = tile >> 4, tc = tile & 15;
        #pragma unroll
        for (int it = 0; it < 4; ++it) {
            int r  = it * 16 + (tid >> 4);
            int c0 = (tid & 15) * 4;
            float4 v = *(const float4*)(src + (size_t)(tr * 64 + r) * 1024 + tc * 64 + c0);
            tl[(c0 + 0) * 68 + r] = f32_to_bf16_rne(v.x);
            tl[(c0 + 1) * 68 + r] = f32_to_bf16_rne(v.y);
            tl[(c0 + 2) * 68 + r] = f32_to_bf16_rne(v.z);
            tl[(c0 + 3) * 68 + r] = f32_to_bf16_rne(v.w);
        }
        __syncthreads();
        #pragma unroll
        for (int it = 0; it < 4; ++it) {
            int c  = it * 16 + (tid >> 4);
            int r0 = (tid & 15) * 4;
            ushort4 o;
            o.x = tl[c * 68 + r0 + 0]; o.y = tl[c * 68 + r0 + 1];
            o.z = tl[c * 68 + r0 + 2]; o.w = tl[c * 68 + r0 + 3];
            *(ushort4*)(w16 + slot * 1048576 + (size_t)(tc * 64 + c) * 1024 + tr * 64 + r0) = o;
        }
    } else if (b < 10000) {
        // bfinal[row] = bo[row] + dot(Wo[row,:], bv)
        int bb = b - 9984;
        int lane = tid & 63, wv_ = tid >> 6;
        int rowBase = bb * 64 + wv_ * 16;
        for (int rr = 0; rr < 16; ++rr) {
            int row = rowBase + rr;
            float partial = 0.f;
            #pragma unroll
            for (int t2 = 0; t2 < 16; ++t2) {
                int h = t2 * 64 + lane;
                partial += Wo[(size_t)row * 1024 + h] * bv[h];
            }
            #pragma unroll
            for (int off = 32; off > 0; off >>= 1)
                partial += __shfl_xor(partial, off, 64);
            if (lane == 0) bfinal[row] = bo[row] + partial;
        }
    } else {
        // g0[j] += sum_{h in block range} bq[h] * Wk[h, j]
        // 64 blocks x 16 rows, coalesced float4 row reads, atomic partials.
        int bb = b - 10000;
        int j0 = tid * 4;
        float ax = 0.f, ay = 0.f, az = 0.f, aw = 0.f;
        #pragma unroll
        for (int r = 0; r < 16; ++r) {
            int h = bb * 16 + r;
            float s = bq[h];
            float4 w = *(const float4*)(Wk + (size_t)h * 1024 + j0);
            ax += s * w.x; ay += s * w.y; az += s * w.z; aw += s * w.w;
        }
        atomicAdd(&g0[j0 + 0], ax); atomicAdd(&g0[j0 + 1], ay);
        atomicAdd(&g0[j0 + 2], az); atomicAdd(&g0[j0 + 3], aw);
    }
}

// ---------------------------------------------------------------------------
// Proven 128^2 K-loop (R5 codegen) — gf and qgv.
// ---------------------------------------------------------------------------
__device__ __forceinline__ void gemm_core(
    const unsigned short* __restrict__ Ab,
    const unsigned short* __restrict__ Bb,
    unsigned short* ldsA, unsigned short* ldsB,
    int mBase, int nBase, int lane, int wave, int K, f32x4 (&acc)[4][4])
{
    const int quad = lane >> 4;
    const int l16  = lane & 15;
    const int wr   = wave >> 1;
    const int wc   = wave & 1;

    for (int k0 = 0; k0 < K; k0 += BK) {
        #pragma unroll
        for (int i = 0; i < 4; ++i) {
            int base = (i * 4 + wave) * 64;
            int s    = base + lane;
            int row  = s >> 3;
            int col  = ((s ^ (s >> 3)) & 7) * 8;
            __builtin_amdgcn_global_load_lds(
                (const __attribute__((address_space(1))) void*)(Ab + (size_t)(mBase + row) * K + (size_t)(k0 + col)),
                (__attribute__((address_space(3))) void*)(&ldsA[base * 8]),
                16, 0, 0);
        }
        #pragma unroll
        for (int i = 0; i < 4; ++i) {
            int base = (i * 4 + wave) * 64;
            int s    = base + lane;
            int row  = s >> 3;
            int col  = ((s ^ (s >> 3)) & 7) * 8;
            __builtin_amdgcn_global_load_lds(
                (const __attribute__((address_space(1))) void*)(Bb + (size_t)(nBase + row) * K + (size_t)(k0 + col)),
                (__attribute__((address_space(3))) void*)(&ldsB[base * 8]),
                16, 0, 0);
        }
        __syncthreads();

        #pragma unroll
        for (int kk = 0; kk < 2; ++kk) {
            bf16x8 af[4], bfv[4];
            #pragma unroll
            for (int mi = 0; mi < 4; ++mi) {
                int r = wr * 64 + mi * 16 + l16;
                int c = kk * 4 + quad;
                af[mi] = *(const bf16x8*)(&ldsA[r * BK + (((c ^ r) & 7) << 3)]);
            }
            #pragma unroll
            for (int ni = 0; ni < 4; ++ni) {
                int r = wc * 64 + ni * 16 + l16;
                int c = kk * 4 + quad;
                bfv[ni] = *(const bf16x8*)(&ldsB[r * BK + (((c ^ r) & 7) << 3)]);
            }
            #pragma unroll
            for (int mi = 0; mi < 4; ++mi)
                #pragma unroll
                for (int ni = 0; ni < 4; ++ni)
                    acc[mi][ni] = __builtin_amdgcn_mfma_f32_16x16x32_bf16(
                        af[mi], bfv[ni], acc[mi][ni], 0, 0, 0);
        }
        __syncthreads();
    }
}

// ---------------------------------------------------------------------------
// Small dispatch (128 blocks): Gt = WkT.(WqT)^T and F = Wo.(WvT)^T.
// ---------------------------------------------------------------------------
__global__ __launch_bounds__(256) void gemm_gf(
    const unsigned short* __restrict__ w16,
    unsigned short* __restrict__ Gt16, unsigned short* __restrict__ F16)
{
    __shared__ unsigned short ldsA[BM * BK];
    __shared__ unsigned short ldsB[BN * BK];

    const int l = blockIdx.x, tid = threadIdx.x;
    const unsigned short *Ab, *Bb;
    unsigned short* Cb;
    int f;
    if (l < 64) { f = l;      Ab = w16 + (size_t)1 * 1048576; Bb = w16;                        Cb = Gt16; }
    else        { f = l - 64; Ab = w16 + (size_t)2 * 1048576; Bb = w16 + (size_t)3 * 1048576; Cb = F16;  }
    int mBase = (f >> 3) * BM, nBase = (f & 7) * BN;

    const int lane = tid & 63, wave = tid >> 6;
    const int quad = lane >> 4, l16 = lane & 15;
    const int wr = wave >> 1, wc = wave & 1;

    f32x4 acc[4][4] = {};
    gemm_core(Ab, Bb, ldsA, ldsB, mBase, nBase, lane, wave, 1024, acc);

    #pragma unroll
    for (int mi = 0; mi < 4; ++mi)
        #pragma unroll
        for (int ni = 0; ni < 4; ++ni) {
            int col = nBase + wc * 64 + ni * 16 + l16;
            #pragma unroll
            for (int r = 0; r < 4; ++r) {
                int row = mBase + wr * 64 + mi * 16 + quad * 4 + r;
                Cb[(size_t)row * 1024 + col] = f32_to_bf16_rne(acc[mi][ni][r]);
            }
        }
}

// ---------------------------------------------------------------------------
// qg = x.Gt^T + g0 (512 tiles) and Vot[b] = F.x_b^T (512 tiles), merged.
// 1024 blocks, XCD-contiguous.
// ---------------------------------------------------------------------------
__global__ __launch_bounds__(256) void gemm_qgv(
    const unsigned short* __restrict__ x16,
    const unsigned short* __restrict__ Gt16,
    const unsigned short* __restrict__ F16,
    const float* __restrict__ g0,
    unsigned short* __restrict__ qg16,
    unsigned short* __restrict__ vot16)
{
    __shared__ unsigned short ldsA[BM * BK];
    __shared__ unsigned short ldsB[BN * BK];

    int l   = blockIdx.x;                 // 1024 = 8 * 128
    int idx = (l & 7) * 128 + (l >> 3);   // XCD-contiguous

    const unsigned short *Ab, *Bb;
    unsigned short* Cb;
    const float* bias;
    int mBase, nBase, Cstride;
    if (idx < 512) {
        // qg: M=8192 (both batches), N=1024, K=1024
        mBase = (idx >> 3) * BM; nBase = (idx & 7) * BN;
        Ab = x16; Bb = Gt16; Cb = qg16; bias = g0; Cstride = 1024;
    } else {
        // Vot[b]: M=1024, N=4096, K=1024
        int v = idx - 512;
        int zb = v >> 8, t2 = v & 255;
        mBase = (t2 >> 5) * BM; nBase = (t2 & 31) * BN;
        Ab = F16; Bb = x16 + (size_t)zb * 4096 * 1024;
        Cb = vot16 + (size_t)zb * 1024 * 4096; bias = nullptr; Cstride = 4096;
    }

    const int tid  = threadIdx.x;
    const int lane = tid & 63;
    const int wave = tid >> 6;
    const int quad = lane >> 4;
    const int l16  = lane & 15;
    const int wr   = wave >> 1;
    const int wc   = wave & 1;

    f32x4 acc[4][4] = {};
    gemm_core(Ab, Bb, ldsA, ldsB, mBase, nBase, lane, wave, 1024, acc);

    #pragma unroll
    for (int mi = 0; mi < 4; ++mi)
        #pragma unroll
        for (int ni = 0; ni < 4; ++ni) {
            int col = nBase + wc * 64 + ni * 16 + l16;
            float b = bias ? bias[col] : 0.f;
            #pragma unroll
            for (int r = 0; r < 4; ++r) {
                int row = mBase + wr * 64 + mi * 16 + quad * 4 + r;
                Cb[(size_t)row * Cstride + col] = f32_to_bf16_rne(acc[mi][ni][r] + b);
            }
        }
}

// ---------------------------------------------------------------------------
// Phase-split GEMM (R10-corrected m201 schedule). 8 waves (2m x 4n), BK=64,
// double-buffered xor-swizzled LDS, global_load_lds(16B), counted vmcnt once
// per K-tile (never 0 in steady state). Phase = {ds_read subtile + stage
// issue + [vmcnt] -> s_barrier -> lgkmcnt(0)+sched_barrier(0) -> setprio(1)
// 16xMFMA setprio(0) -> s_barrier}.
// MODE 3 (scores, 256x256): C bf16 = exp(acc*alpha), atomic fp32 rowsums.
// MODE 6 (final, 128x256):  C fp32 = acc/rowsum + b0.
// ---------------------------------------------------------------------------
template <int MODE, int BMt, int BNt>
__global__ __launch_bounds__(512) void gemm8p(
    const unsigned short* __restrict__ A,
    const unsigned short* __restrict__ Bt,
    void* __restrict__ C,
    const float* __restrict__ b0, float* __restrict__ rowsum,
    float alpha, int M, int N, int K,
    long long aZ, long long bZ, long long cZ,
    int MBt, int NB)
{
    constexpr int RW  = BMt / 2;           // rows per wave
    constexpr int CW  = BNt / 4;           // cols per wave (= 64)
    constexpr int MI  = RW / 16;           // m-frags per wave
    constexpr int NI  = CW / 16;           // n-frags per wave (= 4)
    constexpr int NPH = MI / 2;            // phases per K-tile
    constexpr int BL  = (BNt * 64 / 512) / 8;  // B loads/wave/K-tile (= 4)
    constexpr int NWT = BL + NPH - 1;      // steady-state counted vmcnt

    __shared__ __align__(16) unsigned short ldsA[2][BMt * 64];
    __shared__ __align__(16) unsigned short ldsB[2][BNt * 64];

    const int l   = blockIdx.x;
    const int xcd = l & 7;
    const int t   = l >> 3;
    const int MBX = MBt >> 1;
    const int NBX = NB >> 2;
    const int mbl = t % MBX;
    const int r1  = t / MBX;
    const int nbi = r1 % NBX;
    const int zb  = r1 / NBX;
    const int mb  = (xcd >> 2) * MBX + mbl;
    const int nb  = (xcd & 3) * NBX + nbi;

    const unsigned short* Ab = A  + (size_t)zb * aZ;
    const unsigned short* Bb = Bt + (size_t)zb * bZ;

    const int tid  = threadIdx.x;
    const int lane = tid & 63;
    const int wave = tid >> 6;
    const int quad = lane >> 4;
    const int l16  = lane & 15;
    const int wr   = wave >> 2;            // 0..1
    const int wc   = wave & 3;             // 0..3
    const int mBase = mb * BMt;
    const int nBase = nb * BNt;
    const int NT    = K >> 6;

    // each wave stages one 8-row octet per A-strip-half and BL octets of B
    const int aRow0 = ((wave & 4) ? RW : 0) + (wave & 3) * 8;

    auto stageA = [&](int p, int kt, int q) {
        const int rowbase = aRow0 + q * 32;
        const int row = rowbase + (lane >> 3);
        const int col = (((lane & 7) ^ row) & 7) << 3;   // pre-swizzled source
        __builtin_amdgcn_global_load_lds(
            (const __attribute__((address_space(1))) void*)(
                Ab + (size_t)(mBase + row) * K + (size_t)((kt << 6) + col)),
            (__attribute__((address_space(3))) void*)(&ldsA[p][rowbase * 64]),
            16, 0, 0);
    };
    auto stageB = [&](int p, int kt) {
        #pragma unroll
        for (int i = 0; i < BL; ++i) {
            const int g   = wave * BL + i;
            const int row = (g << 3) + (lane >> 3);
            const int col = (((lane & 7) ^ row) & 7) << 3;
            __builtin_amdgcn_global_load_lds(
                (const __attribute__((address_space(1))) void*)(
                    Bb + (size_t)(nBase + row) * K + (size_t)((kt << 6) + col)),
                (__attribute__((address_space(3))) void*)(&ldsB[p][g << 9]),
                16, 0, 0);
        }
    };

    bf16x8 bf[NI][2];
    bf16x8 af[2][2];
    auto ldB = [&](int p) {
        #pragma unroll
        for (int n2 = 0; n2 < NI; ++n2)
            #pragma unroll
            for (int kk = 0; kk < 2; ++kk) {
                const int r = wc * CW + n2 * 16 + l16;
                const int c = kk * 4 + quad;
                bf[n2][kk] = *(const bf16x8*)&ldsB[p][r * 64 + (((c ^ r) & 7) << 3)];
            }
    };
    auto ldA = [&](int p, int q) {
        #pragma unroll
        for (int m2 = 0; m2 < 2; ++m2)
            #pragma unroll
            for (int kk = 0; kk < 2; ++kk) {
                const int r = wr * RW + (q * 2 + m2) * 16 + l16;
                const int c = kk * 4 + quad;
                af[m2][kk] = *(const bf16x8*)&ldsA[p][r * 64 + (((c ^ r) & 7) << 3)];
            }
    };

    f32x4 acc[MI][NI] = {};

    // ---- prologue: tile0 fully + tile1 all but its last strip ----
    stageB(0, 0);
    #pragma unroll
    for (int q = 0; q < NPH; ++q) stageA(0, 0, q);
    if (NT > 1) {
        stageB(1, 1);
        #pragma unroll
        for (int q = 0; q < NPH - 1; ++q) stageA(1, 1, q);
        asm volatile("s_waitcnt vmcnt(%0)" :: "n"(NWT) : "memory");
    } else {
        asm volatile("s_waitcnt vmcnt(0)" ::: "memory");
    }
    __builtin_amdgcn_s_barrier();

    // ---- main loop ----
    for (int kt = 0; kt < NT; ++kt) {
        const int p = kt & 1;
        #pragma unroll
        for (int q = 0; q < NPH; ++q) {
            if (q == 0) ldB(p);
            ldA(p, q);
            if (q == 0) {
                if (kt + 1 < NT) stageA(p ^ 1, kt + 1, NPH - 1);
            } else if (q == 1) {
                if (kt + 2 < NT) { stageB(p, kt + 2); stageA(p, kt + 2, 0); }
            } else {
                if (kt + 2 < NT) stageA(p, kt + 2, q - 1);
            }
            if (q == NPH - 1) {
                if (kt + 2 < NT) {
                    asm volatile("s_waitcnt vmcnt(%0)" :: "n"(NWT) : "memory");
                } else if (kt + 1 < NT) {
                    asm volatile("s_waitcnt vmcnt(0)" ::: "memory");
                }
            }
            __builtin_amdgcn_s_barrier();
            // pin all of this wave's ds_reads complete before the end
            // barrier (slot-reuse race-freedom) and keep MFMAs from
            // hoisting above it (rule #18).
            asm volatile("s_waitcnt lgkmcnt(0)" ::: "memory");
            __builtin_amdgcn_sched_barrier(0);
            __builtin_amdgcn_s_setprio(1);
            #pragma unroll
            for (int m2 = 0; m2 < 2; ++m2)
                #pragma unroll
                for (int n2 = 0; n2 < NI; ++n2)
                    #pragma unroll
                    for (int kk = 0; kk < 2; ++kk)
                        acc[q * 2 + m2][n2] = __builtin_amdgcn_mfma_f32_16x16x32_bf16(
                            af[m2][kk], bf[n2][kk], acc[q * 2 + m2][n2], 0, 0, 0);
            __builtin_amdgcn_s_setprio(0);
            __builtin_amdgcn_s_barrier();
        }
    }

    // ---- epilogues. C/D layout: col = l16, row = quad*4 + reg ----
    if constexpr (MODE == 3) {
        unsigned short* Pz = (unsigned short*)C + (size_t)zb * cZ;
        float* rs = rowsum + (size_t)zb * M;
        #pragma unroll
        for (int mi = 0; mi < MI; ++mi) {
            #pragma unroll
            for (int r = 0; r < 4; ++r) {
                const int row = mBase + wr * RW + mi * 16 + quad * 4 + r;
                float e[NI];
                float partial = 0.f;
                #pragma unroll
                for (int ni = 0; ni < NI; ++ni) {
                    e[ni] = __expf(acc[mi][ni][r] * alpha);
                    partial += e[ni];
                }
                #pragma unroll
                for (int ni = 0; ni < NI; ++ni) {
                    const int col = nBase + wc * CW + ni * 16 + l16;
                    Pz[(size_t)row * N + col] = f32_to_bf16_rne(e[ni]);
                }
                #pragma unroll
                for (int off = 1; off < 16; off <<= 1)
                    partial += __shfl_xor(partial, off, 64);
                if (l16 == 0) atomicAdd(&rs[row], partial);
            }
        }
    } else {  // MODE 6
        float* Cz = (float*)C + (size_t)zb * cZ;
        const float* rs = rowsum + (size_t)zb * M;
        #pragma unroll
        for (int mi = 0; mi < MI; ++mi) {
            #pragma unroll
            for (int r = 0; r < 4; ++r) {
                const int row = mBase + wr * RW + mi * 16 + quad * 4 + r;
                const float inv = 1.f / rs[row];
                #pragma unroll
                for (int ni = 0; ni < NI; ++ni) {
                    const int col = nBase + wc * CW + ni * 16 + l16;
                    Cz[(size_t)row * N + col] = acc[mi][ni][r] * inv + b0[col];
                }
            }
        }
    }
}

// ---------------------------------------------------------------------------
extern "C" void kernel_launch(void* const* d_in, const int* in_sizes, int n_in,
                              void* d_out, int out_size, void* d_ws, size_t ws_size,
                              hipStream_t stream)
{
    const float* x  = (const float*)d_in[0];
    const float* Wq = (const float*)d_in[1];
    const float* bq = (const float*)d_in[2];
    const float* Wk = (const float*)d_in[3];
    const float* Wv = (const float*)d_in[5];
    const float* bv = (const float*)d_in[6];
    const float* Wo = (const float*)d_in[7];
    const float* bo = (const float*)d_in[8];
    float* out = (float*)d_out;

    const int S = 4096, H = 1024, Bsz = 2;
    const int M = Bsz * S;   // 8192

    char* p = (char*)d_ws;
    auto alloc = [&](size_t bytes) -> char* {
        char* r = p; p += (bytes + 255) & ~(size_t)255; return r;
    };
    // footprint ~124 MiB (ws >= 153 MiB proven in R2)
    unsigned short* w16   = (unsigned short*)alloc((size_t)4 * H * H * 2);  // WqT|WkT|Wo|WvT
    unsigned short* F16   = (unsigned short*)alloc((size_t)H * H * 2);
    unsigned short* Gt16  = (unsigned short*)alloc((size_t)H * H * 2);
    unsigned short* qg16  = (unsigned short*)alloc((size_t)M * H * 2);
    unsigned short* vot16 = (unsigned short*)alloc((size_t)Bsz * H * S * 2); // [B][H][S]
    unsigned short* x16   = (unsigned short*)alloc((size_t)M * H * 2);
    float*          rsum  = (float*)alloc((size_t)M * 4);
    float*          bfin  = (float*)alloc((size_t)H * 4);
    float*          g0    = (float*)alloc((size_t)H * 4);
    unsigned short* p16   = (unsigned short*)alloc((size_t)Bsz * S * S * 2);

    // 0) zero the accumulators (stream-ordered; graph-capturable)
    hipMemsetAsync(rsum, 0, (size_t)M * 4, stream);
    hipMemsetAsync(g0,   0, (size_t)H * 4, stream);

    // 1) converts + transposes + bfinal + distributed-atomic g0
    cvt_all<<<10064, 256, 0, stream>>>(x, Wq, Wk, Wo, Wv, bq, bv, bo,
                                       x16, w16, bfin, g0);

    // 2) Gt = G^T = WkT.WqT^T, F = Wo.WvT^T
    gemm_gf<<<128, 256, 0, stream>>>(w16, Gt16, F16);

    // 3) qg = x.Gt^T + g0  and  Vot[b] = F.x_b^T
    gemm_qgv<<<1024, 256, 0, stream>>>(x16, Gt16, F16, g0, qg16, vot16);

    // 4) P_un[b] = exp((qg.x_b^T)/8) + atomic rowsums  (256x256 phase-split)
    gemm8p<3, 256, 256><<<512, 512, 0, stream>>>(
        qg16, x16, p16, nullptr, rsum, 0.125f, S, S, 1024,
        (long long)S * H, (long long)S * H, (long long)S * S, 16, 16);

    // 5) out[b] = (P_un . Vot^T)/rowsum + bfinal   (128x256 phase-split)
    gemm8p<6, 128, 256><<<256, 512, 0, stream>>>(
        p16, vot16, out, bfin, rsum, 1.f, S, H, 4096,
        (long long)S * S, (long long)H * S, (long long)S * H, 32, 4);
}

// Round 6
// 343.789 us; speedup vs baseline: 1.1217x; 1.0157x over previous
//
#include <hip/hip_runtime.h>
#include <stdint.h>

// ---------------------------------------------------------------------------
// DistributedAttention on MI355X (gfx950)
//   q = x Wq^T + bq ; k = x Wk^T + bk ; v = x Wv^T + bv
//   P = softmax(q k^T / 8) ; out = P v Wo^T + bo
// Factorizations:
//   F  = Wo . Wv                  (2.1 GF, replaces the 17.2 GF v-proj)  [R7]
//   Vot= F . x^T per batch        ([H][S] bf16)                          [R7]
//   G  = Wq^T . Wk  (batch-indep) ; qg = x . G + g0, g0 = bq^T Wk        [R11]
//   scores = qg . x^T   (row-constant terms cancel in softmax)           [R12]
//   P_un = exp(scores / 8)        (bf16 + atomic fp32 rowsums)
//   out  = (P_un . Vot^T)/rowsum + bfinal,  bfinal = bo + Wo.bv
// R14: measurement-driven freeze of per-dispatch variants.
//   R13 A/B result: scores @256^2 8-phase = 94.6 µs / 726 TF vs
//   scores @128^2 2-barrier = 89.7 µs / 766 TF (R12) — the 8-phase port
//   delivers ~half of the m201 reference (both instances), so scores
//   REVERTS to gemm_bt<3> (single instantiation, VGPR 80). final keeps
//   gemm8p<6,128,256> (never in top-5, < gemm_bt<6>'s 96.4 µs from R8).
//   g0 distributed-atomic fix (R13, −29 µs) kept. cvt/gf/qgv unchanged.
// ---------------------------------------------------------------------------

typedef __bf16 bf16x8 __attribute__((ext_vector_type(8)));
typedef float  f32x4  __attribute__((ext_vector_type(4)));

__device__ __forceinline__ unsigned short f32_to_bf16_rne(float f) {
    uint32_t u = __builtin_bit_cast(uint32_t, f);
    uint32_t r = (u + 0x7FFFu + ((u >> 16) & 1u)) >> 16;
    return (unsigned short)r;
}

#define BM 128
#define BN 128
#define BK 64

// ---------------------------------------------------------------------------
// One-dispatch prep, 10064 blocks:
//   [0,8192)        x fp32 -> x16 bf16
//   [8192,9216)     Wo straight convert -> w16 slot 2
//   [9216,9984)     WqT, WkT, WvT 64x64-tile transposes -> slots 0,1,3
//   [9984,10000)    bfinal = bo + Wo.bv
//   [10000,10064)   g0 += bq[h-range]^T Wk[h-range,:]  (64 blocks, each 16
//                   coalesced Wk rows; g0 pre-zeroed by hipMemsetAsync)
// ---------------------------------------------------------------------------
__global__ __launch_bounds__(256) void cvt_all(
    const float* __restrict__ x,
    const float* __restrict__ Wq, const float* __restrict__ Wk,
    const float* __restrict__ Wo, const float* __restrict__ Wv,
    const float* __restrict__ bq,
    const float* __restrict__ bv, const float* __restrict__ bo,
    unsigned short* __restrict__ x16, unsigned short* __restrict__ w16,
    float* __restrict__ bfinal, float* __restrict__ g0)
{
    const int b = blockIdx.x, tid = threadIdx.x;
    if (b < 8192) {
        int i = (b * 256 + tid) * 4;
        float4 v = *(const float4*)(x + i);
        ushort4 o;
        o.x = f32_to_bf16_rne(v.x); o.y = f32_to_bf16_rne(v.y);
        o.z = f32_to_bf16_rne(v.z); o.w = f32_to_bf16_rne(v.w);
        *(ushort4*)(x16 + i) = o;
    } else if (b < 9216) {
        int i = ((b - 8192) * 256 + tid) * 4;
        float4 v = *(const float4*)(Wo + i);
        ushort4 o;
        o.x = f32_to_bf16_rne(v.x); o.y = f32_to_bf16_rne(v.y);
        o.z = f32_to_bf16_rne(v.z); o.w = f32_to_bf16_rne(v.w);
        *(ushort4*)(w16 + (size_t)2 * 1048576 + i) = o;
    } else if (b < 9984) {
        // transpose one 64x64 tile of {Wq,Wk,Wv} into w16 slot {0,1,3}
        __shared__ unsigned short tl[64 * 68];   // [c][r], stride 68
        int t = b - 9216;
        int which = t >> 8;                      // 0:Wq 1:Wk 2:Wv
        const float* src = which == 0 ? Wq : which == 1 ? Wk : Wv;
        size_t slot = which == 0 ? 0 : which == 1 ? 1 : 3;
        int tile = t & 255, tr = tile >> 4, tc = tile & 15;
        #pragma unroll
        for (int it = 0; it < 4; ++it) {
            int r  = it * 16 + (tid >> 4);
            int c0 = (tid & 15) * 4;
            float4 v = *(const float4*)(src + (size_t)(tr * 64 + r) * 1024 + tc * 64 + c0);
            tl[(c0 + 0) * 68 + r] = f32_to_bf16_rne(v.x);
            tl[(c0 + 1) * 68 + r] = f32_to_bf16_rne(v.y);
            tl[(c0 + 2) * 68 + r] = f32_to_bf16_rne(v.z);
            tl[(c0 + 3) * 68 + r] = f32_to_bf16_rne(v.w);
        }
        __syncthreads();
        #pragma unroll
        for (int it = 0; it < 4; ++it) {
            int c  = it * 16 + (tid >> 4);
            int r0 = (tid & 15) * 4;
            ushort4 o;
            o.x = tl[c * 68 + r0 + 0]; o.y = tl[c * 68 + r0 + 1];
            o.z = tl[c * 68 + r0 + 2]; o.w = tl[c * 68 + r0 + 3];
            *(ushort4*)(w16 + slot * 1048576 + (size_t)(tc * 64 + c) * 1024 + tr * 64 + r0) = o;
        }
    } else if (b < 10000) {
        // bfinal[row] = bo[row] + dot(Wo[row,:], bv)
        int bb = b - 9984;
        int lane = tid & 63, wv_ = tid >> 6;
        int rowBase = bb * 64 + wv_ * 16;
        for (int rr = 0; rr < 16; ++rr) {
            int row = rowBase + rr;
            float partial = 0.f;
            #pragma unroll
            for (int t2 = 0; t2 < 16; ++t2) {
                int h = t2 * 64 + lane;
                partial += Wo[(size_t)row * 1024 + h] * bv[h];
            }
            #pragma unroll
            for (int off = 32; off > 0; off >>= 1)
                partial += __shfl_xor(partial, off, 64);
            if (lane == 0) bfinal[row] = bo[row] + partial;
        }
    } else {
        // g0[j] += sum_{h in block range} bq[h] * Wk[h, j]
        // 64 blocks x 16 rows, coalesced float4 row reads, atomic partials.
        int bb = b - 10000;
        int j0 = tid * 4;
        float ax = 0.f, ay = 0.f, az = 0.f, aw = 0.f;
        #pragma unroll
        for (int r = 0; r < 16; ++r) {
            int h = bb * 16 + r;
            float s = bq[h];
            float4 w = *(const float4*)(Wk + (size_t)h * 1024 + j0);
            ax += s * w.x; ay += s * w.y; az += s * w.z; aw += s * w.w;
        }
        atomicAdd(&g0[j0 + 0], ax); atomicAdd(&g0[j0 + 1], ay);
        atomicAdd(&g0[j0 + 2], az); atomicAdd(&g0[j0 + 3], aw);
    }
}

// ---------------------------------------------------------------------------
// Proven 128^2 K-loop (R5 codegen) — gf, qgv, scores.
// ---------------------------------------------------------------------------
__device__ __forceinline__ void gemm_core(
    const unsigned short* __restrict__ Ab,
    const unsigned short* __restrict__ Bb,
    unsigned short* ldsA, unsigned short* ldsB,
    int mBase, int nBase, int lane, int wave, int K, f32x4 (&acc)[4][4])
{
    const int quad = lane >> 4;
    const int l16  = lane & 15;
    const int wr   = wave >> 1;
    const int wc   = wave & 1;

    for (int k0 = 0; k0 < K; k0 += BK) {
        #pragma unroll
        for (int i = 0; i < 4; ++i) {
            int base = (i * 4 + wave) * 64;
            int s    = base + lane;
            int row  = s >> 3;
            int col  = ((s ^ (s >> 3)) & 7) * 8;
            __builtin_amdgcn_global_load_lds(
                (const __attribute__((address_space(1))) void*)(Ab + (size_t)(mBase + row) * K + (size_t)(k0 + col)),
                (__attribute__((address_space(3))) void*)(&ldsA[base * 8]),
                16, 0, 0);
        }
        #pragma unroll
        for (int i = 0; i < 4; ++i) {
            int base = (i * 4 + wave) * 64;
            int s    = base + lane;
            int row  = s >> 3;
            int col  = ((s ^ (s >> 3)) & 7) * 8;
            __builtin_amdgcn_global_load_lds(
                (const __attribute__((address_space(1))) void*)(Bb + (size_t)(nBase + row) * K + (size_t)(k0 + col)),
                (__attribute__((address_space(3))) void*)(&ldsB[base * 8]),
                16, 0, 0);
        }
        __syncthreads();

        #pragma unroll
        for (int kk = 0; kk < 2; ++kk) {
            bf16x8 af[4], bfv[4];
            #pragma unroll
            for (int mi = 0; mi < 4; ++mi) {
                int r = wr * 64 + mi * 16 + l16;
                int c = kk * 4 + quad;
                af[mi] = *(const bf16x8*)(&ldsA[r * BK + (((c ^ r) & 7) << 3)]);
            }
            #pragma unroll
            for (int ni = 0; ni < 4; ++ni) {
                int r = wc * 64 + ni * 16 + l16;
                int c = kk * 4 + quad;
                bfv[ni] = *(const bf16x8*)(&ldsB[r * BK + (((c ^ r) & 7) << 3)]);
            }
            #pragma unroll
            for (int mi = 0; mi < 4; ++mi)
                #pragma unroll
                for (int ni = 0; ni < 4; ++ni)
                    acc[mi][ni] = __builtin_amdgcn_mfma_f32_16x16x32_bf16(
                        af[mi], bfv[ni], acc[mi][ni], 0, 0, 0);
        }
        __syncthreads();
    }
}

// ---------------------------------------------------------------------------
// Small dispatch (128 blocks): Gt = WkT.(WqT)^T and F = Wo.(WvT)^T.
// ---------------------------------------------------------------------------
__global__ __launch_bounds__(256) void gemm_gf(
    const unsigned short* __restrict__ w16,
    unsigned short* __restrict__ Gt16, unsigned short* __restrict__ F16)
{
    __shared__ unsigned short ldsA[BM * BK];
    __shared__ unsigned short ldsB[BN * BK];

    const int l = blockIdx.x, tid = threadIdx.x;
    const unsigned short *Ab, *Bb;
    unsigned short* Cb;
    int f;
    if (l < 64) { f = l;      Ab = w16 + (size_t)1 * 1048576; Bb = w16;                        Cb = Gt16; }
    else        { f = l - 64; Ab = w16 + (size_t)2 * 1048576; Bb = w16 + (size_t)3 * 1048576; Cb = F16;  }
    int mBase = (f >> 3) * BM, nBase = (f & 7) * BN;

    const int lane = tid & 63, wave = tid >> 6;
    const int quad = lane >> 4, l16 = lane & 15;
    const int wr = wave >> 1, wc = wave & 1;

    f32x4 acc[4][4] = {};
    gemm_core(Ab, Bb, ldsA, ldsB, mBase, nBase, lane, wave, 1024, acc);

    #pragma unroll
    for (int mi = 0; mi < 4; ++mi)
        #pragma unroll
        for (int ni = 0; ni < 4; ++ni) {
            int col = nBase + wc * 64 + ni * 16 + l16;
            #pragma unroll
            for (int r = 0; r < 4; ++r) {
                int row = mBase + wr * 64 + mi * 16 + quad * 4 + r;
                Cb[(size_t)row * 1024 + col] = f32_to_bf16_rne(acc[mi][ni][r]);
            }
        }
}

// ---------------------------------------------------------------------------
// qg = x.Gt^T + g0 (512 tiles) and Vot[b] = F.x_b^T (512 tiles), merged.
// 1024 blocks, XCD-contiguous.
// ---------------------------------------------------------------------------
__global__ __launch_bounds__(256) void gemm_qgv(
    const unsigned short* __restrict__ x16,
    const unsigned short* __restrict__ Gt16,
    const unsigned short* __restrict__ F16,
    const float* __restrict__ g0,
    unsigned short* __restrict__ qg16,
    unsigned short* __restrict__ vot16)
{
    __shared__ unsigned short ldsA[BM * BK];
    __shared__ unsigned short ldsB[BN * BK];

    int l   = blockIdx.x;                 // 1024 = 8 * 128
    int idx = (l & 7) * 128 + (l >> 3);   // XCD-contiguous

    const unsigned short *Ab, *Bb;
    unsigned short* Cb;
    const float* bias;
    int mBase, nBase, Cstride;
    if (idx < 512) {
        // qg: M=8192 (both batches), N=1024, K=1024
        mBase = (idx >> 3) * BM; nBase = (idx & 7) * BN;
        Ab = x16; Bb = Gt16; Cb = qg16; bias = g0; Cstride = 1024;
    } else {
        // Vot[b]: M=1024, N=4096, K=1024
        int v = idx - 512;
        int zb = v >> 8, t2 = v & 255;
        mBase = (t2 >> 5) * BM; nBase = (t2 & 31) * BN;
        Ab = F16; Bb = x16 + (size_t)zb * 4096 * 1024;
        Cb = vot16 + (size_t)zb * 1024 * 4096; bias = nullptr; Cstride = 4096;
    }

    const int tid  = threadIdx.x;
    const int lane = tid & 63;
    const int wave = tid >> 6;
    const int quad = lane >> 4;
    const int l16  = lane & 15;
    const int wr   = wave >> 1;
    const int wc   = wave & 1;

    f32x4 acc[4][4] = {};
    gemm_core(Ab, Bb, ldsA, ldsB, mBase, nBase, lane, wave, 1024, acc);

    #pragma unroll
    for (int mi = 0; mi < 4; ++mi)
        #pragma unroll
        for (int ni = 0; ni < 4; ++ni) {
            int col = nBase + wc * 64 + ni * 16 + l16;
            float b = bias ? bias[col] : 0.f;
            #pragma unroll
            for (int r = 0; r < 4; ++r) {
                int row = mBase + wr * 64 + mi * 16 + quad * 4 + r;
                Cb[(size_t)row * Cstride + col] = f32_to_bf16_rne(acc[mi][ni][r] + b);
            }
        }
}

// ---------------------------------------------------------------------------
// scores: z-batched A.Bt^T, 128^2 proven path (fastest measured: 89.7 µs).
// C bf16 = exp(acc * alpha), atomic fp32 rowsums.
// ---------------------------------------------------------------------------
__global__ __launch_bounds__(256) void gemm_sc(
    const unsigned short* __restrict__ A,
    const unsigned short* __restrict__ Bt,
    unsigned short* __restrict__ C,
    float* __restrict__ rowsum,
    float alpha, int M, int N, int K,
    long long aZ, long long bZ, long long cZ)
{
    __shared__ unsigned short ldsA[BM * BK];
    __shared__ unsigned short ldsB[BN * BK];

    const int NB = gridDim.x, MBt = gridDim.y;
    int l  = blockIdx.x + gridDim.x * (blockIdx.y + gridDim.y * blockIdx.z);
    int xcd = l & 7;
    int t   = l >> 3;
    int MBX = MBt >> 1;
    int NBX = NB >> 2;
    int mbl = t % MBX;
    int r1  = t / MBX;
    int nbi = r1 % NBX;
    int zb  = r1 / NBX;
    int mb  = (xcd >> 2) * MBX + mbl;
    int nb  = (xcd & 3) * NBX + nbi;

    const unsigned short* Ab = A  + (size_t)zb * aZ;
    const unsigned short* Bb = Bt + (size_t)zb * bZ;

    const int tid  = threadIdx.x;
    const int lane = tid & 63;
    const int wave = tid >> 6;
    const int quad = lane >> 4;
    const int l16  = lane & 15;
    const int wr   = wave >> 1;
    const int wc   = wave & 1;
    const int mBase = mb * BM;
    const int nBase = nb * BN;

    f32x4 acc[4][4] = {};
    gemm_core(Ab, Bb, ldsA, ldsB, mBase, nBase, lane, wave, K, acc);

    unsigned short* Pz = C + (size_t)zb * cZ;
    float* rs = rowsum + (size_t)zb * M;
    #pragma unroll
    for (int mi = 0; mi < 4; ++mi) {
        #pragma unroll
        for (int r = 0; r < 4; ++r) {
            int row = mBase + wr * 64 + mi * 16 + quad * 4 + r;
            float e[4];
            float partial = 0.f;
            #pragma unroll
            for (int ni = 0; ni < 4; ++ni) {
                e[ni] = __expf(acc[mi][ni][r] * alpha);
                partial += e[ni];
            }
            #pragma unroll
            for (int ni = 0; ni < 4; ++ni) {
                int col = nBase + wc * 64 + ni * 16 + l16;
                Pz[(size_t)row * N + col] = f32_to_bf16_rne(e[ni]);
            }
            #pragma unroll
            for (int off = 1; off < 16; off <<= 1)
                partial += __shfl_xor(partial, off, 64);
            if (l16 == 0) atomicAdd(&rs[row], partial);
        }
    }
}

// ---------------------------------------------------------------------------
// final: phase-split GEMM (R10-corrected m201 schedule), 128x256, K=4096.
// 8 waves (2m x 4n), BK=64, double-buffered xor-swizzled LDS,
// global_load_lds(16B), counted vmcnt once per K-tile (never 0 in steady
// state). Phase = {ds_read subtile + stage issue + [vmcnt] -> s_barrier ->
// lgkmcnt(0)+sched_barrier(0) -> setprio(1) 16xMFMA setprio(0) -> s_barrier}.
// C fp32 = acc/rowsum + b0.
// ---------------------------------------------------------------------------
template <int BMt, int BNt>
__global__ __launch_bounds__(512) void gemm8p(
    const unsigned short* __restrict__ A,
    const unsigned short* __restrict__ Bt,
    float* __restrict__ C,
    const float* __restrict__ b0, const float* __restrict__ rowsum,
    int M, int N, int K,
    long long aZ, long long bZ, long long cZ,
    int MBt, int NB)
{
    constexpr int RW  = BMt / 2;           // rows per wave
    constexpr int CW  = BNt / 4;           // cols per wave (= 64)
    constexpr int MI  = RW / 16;           // m-frags per wave
    constexpr int NI  = CW / 16;           // n-frags per wave (= 4)
    constexpr int NPH = MI / 2;            // phases per K-tile
    constexpr int BL  = (BNt * 64 / 512) / 8;  // B loads/wave/K-tile (= 4)
    constexpr int NWT = BL + NPH - 1;      // steady-state counted vmcnt

    __shared__ __align__(16) unsigned short ldsA[2][BMt * 64];
    __shared__ __align__(16) unsigned short ldsB[2][BNt * 64];

    const int l   = blockIdx.x;
    const int xcd = l & 7;
    const int t   = l >> 3;
    const int MBX = MBt >> 1;
    const int NBX = NB >> 2;
    const int mbl = t % MBX;
    const int r1  = t / MBX;
    const int nbi = r1 % NBX;
    const int zb  = r1 / NBX;
    const int mb  = (xcd >> 2) * MBX + mbl;
    const int nb  = (xcd & 3) * NBX + nbi;

    const unsigned short* Ab = A  + (size_t)zb * aZ;
    const unsigned short* Bb = Bt + (size_t)zb * bZ;

    const int tid  = threadIdx.x;
    const int lane = tid & 63;
    const int wave = tid >> 6;
    const int quad = lane >> 4;
    const int l16  = lane & 15;
    const int wr   = wave >> 2;            // 0..1
    const int wc   = wave & 3;             // 0..3
    const int mBase = mb * BMt;
    const int nBase = nb * BNt;
    const int NT    = K >> 6;

    // each wave stages one 8-row octet per A-strip-half and BL octets of B
    const int aRow0 = ((wave & 4) ? RW : 0) + (wave & 3) * 8;

    auto stageA = [&](int p, int kt, int q) {
        const int rowbase = aRow0 + q * 32;
        const int row = rowbase + (lane >> 3);
        const int col = (((lane & 7) ^ row) & 7) << 3;   // pre-swizzled source
        __builtin_amdgcn_global_load_lds(
            (const __attribute__((address_space(1))) void*)(
                Ab + (size_t)(mBase + row) * K + (size_t)((kt << 6) + col)),
            (__attribute__((address_space(3))) void*)(&ldsA[p][rowbase * 64]),
            16, 0, 0);
    };
    auto stageB = [&](int p, int kt) {
        #pragma unroll
        for (int i = 0; i < BL; ++i) {
            const int g   = wave * BL + i;
            const int row = (g << 3) + (lane >> 3);
            const int col = (((lane & 7) ^ row) & 7) << 3;
            __builtin_amdgcn_global_load_lds(
                (const __attribute__((address_space(1))) void*)(
                    Bb + (size_t)(nBase + row) * K + (size_t)((kt << 6) + col)),
                (__attribute__((address_space(3))) void*)(&ldsB[p][g << 9]),
                16, 0, 0);
        }
    };

    bf16x8 bf[NI][2];
    bf16x8 af[2][2];
    auto ldB = [&](int p) {
        #pragma unroll
        for (int n2 = 0; n2 < NI; ++n2)
            #pragma unroll
            for (int kk = 0; kk < 2; ++kk) {
                const int r = wc * CW + n2 * 16 + l16;
                const int c = kk * 4 + quad;
                bf[n2][kk] = *(const bf16x8*)&ldsB[p][r * 64 + (((c ^ r) & 7) << 3)];
            }
    };
    auto ldA = [&](int p, int q) {
        #pragma unroll
        for (int m2 = 0; m2 < 2; ++m2)
            #pragma unroll
            for (int kk = 0; kk < 2; ++kk) {
                const int r = wr * RW + (q * 2 + m2) * 16 + l16;
                const int c = kk * 4 + quad;
                af[m2][kk] = *(const bf16x8*)&ldsA[p][r * 64 + (((c ^ r) & 7) << 3)];
            }
    };

    f32x4 acc[MI][NI] = {};

    // ---- prologue: tile0 fully + tile1 all but its last strip ----
    stageB(0, 0);
    #pragma unroll
    for (int q = 0; q < NPH; ++q) stageA(0, 0, q);
    if (NT > 1) {
        stageB(1, 1);
        #pragma unroll
        for (int q = 0; q < NPH - 1; ++q) stageA(1, 1, q);
        asm volatile("s_waitcnt vmcnt(%0)" :: "n"(NWT) : "memory");
    } else {
        asm volatile("s_waitcnt vmcnt(0)" ::: "memory");
    }
    __builtin_amdgcn_s_barrier();

    // ---- main loop ----
    for (int kt = 0; kt < NT; ++kt) {
        const int p = kt & 1;
        #pragma unroll
        for (int q = 0; q < NPH; ++q) {
            if (q == 0) ldB(p);
            ldA(p, q);
            if (q == 0) {
                if (kt + 1 < NT) stageA(p ^ 1, kt + 1, NPH - 1);
            } else if (q == 1) {
                if (kt + 2 < NT) { stageB(p, kt + 2); stageA(p, kt + 2, 0); }
            } else {
                if (kt + 2 < NT) stageA(p, kt + 2, q - 1);
            }
            if (q == NPH - 1) {
                if (kt + 2 < NT) {
                    asm volatile("s_waitcnt vmcnt(%0)" :: "n"(NWT) : "memory");
                } else if (kt + 1 < NT) {
                    asm volatile("s_waitcnt vmcnt(0)" ::: "memory");
                }
            }
            __builtin_amdgcn_s_barrier();
            // pin all of this wave's ds_reads complete before the end
            // barrier (slot-reuse race-freedom) and keep MFMAs from
            // hoisting above it (rule #18).
            asm volatile("s_waitcnt lgkmcnt(0)" ::: "memory");
            __builtin_amdgcn_sched_barrier(0);
            __builtin_amdgcn_s_setprio(1);
            #pragma unroll
            for (int m2 = 0; m2 < 2; ++m2)
                #pragma unroll
                for (int n2 = 0; n2 < NI; ++n2)
                    #pragma unroll
                    for (int kk = 0; kk < 2; ++kk)
                        acc[q * 2 + m2][n2] = __builtin_amdgcn_mfma_f32_16x16x32_bf16(
                            af[m2][kk], bf[n2][kk], acc[q * 2 + m2][n2], 0, 0, 0);
            __builtin_amdgcn_s_setprio(0);
            __builtin_amdgcn_s_barrier();
        }
    }

    // ---- epilogue. C/D layout: col = l16, row = quad*4 + reg ----
    {
        float* Cz = C + (size_t)zb * cZ;
        const float* rs = rowsum + (size_t)zb * M;
        #pragma unroll
        for (int mi = 0; mi < MI; ++mi) {
            #pragma unroll
            for (int r = 0; r < 4; ++r) {
                const int row = mBase + wr * RW + mi * 16 + quad * 4 + r;
                const float inv = 1.f / rs[row];
                #pragma unroll
                for (int ni = 0; ni < NI; ++ni) {
                    const int col = nBase + wc * CW + ni * 16 + l16;
                    Cz[(size_t)row * N + col] = acc[mi][ni][r] * inv + b0[col];
                }
            }
        }
    }
}

// ---------------------------------------------------------------------------
extern "C" void kernel_launch(void* const* d_in, const int* in_sizes, int n_in,
                              void* d_out, int out_size, void* d_ws, size_t ws_size,
                              hipStream_t stream)
{
    const float* x  = (const float*)d_in[0];
    const float* Wq = (const float*)d_in[1];
    const float* bq = (const float*)d_in[2];
    const float* Wk = (const float*)d_in[3];
    const float* Wv = (const float*)d_in[5];
    const float* bv = (const float*)d_in[6];
    const float* Wo = (const float*)d_in[7];
    const float* bo = (const float*)d_in[8];
    float* out = (float*)d_out;

    const int S = 4096, H = 1024, Bsz = 2;
    const int M = Bsz * S;   // 8192

    char* p = (char*)d_ws;
    auto alloc = [&](size_t bytes) -> char* {
        char* r = p; p += (bytes + 255) & ~(size_t)255; return r;
    };
    // footprint ~124 MiB (ws >= 153 MiB proven in R2)
    unsigned short* w16   = (unsigned short*)alloc((size_t)4 * H * H * 2);  // WqT|WkT|Wo|WvT
    unsigned short* F16   = (unsigned short*)alloc((size_t)H * H * 2);
    unsigned short* Gt16  = (unsigned short*)alloc((size_t)H * H * 2);
    unsigned short* qg16  = (unsigned short*)alloc((size_t)M * H * 2);
    unsigned short* vot16 = (unsigned short*)alloc((size_t)Bsz * H * S * 2); // [B][H][S]
    unsigned short* x16   = (unsigned short*)alloc((size_t)M * H * 2);
    float*          rsum  = (float*)alloc((size_t)M * 4);
    float*          bfin  = (float*)alloc((size_t)H * 4);
    float*          g0    = (float*)alloc((size_t)H * 4);
    unsigned short* p16   = (unsigned short*)alloc((size_t)Bsz * S * S * 2);

    // 0) zero the accumulators (stream-ordered; graph-capturable)
    hipMemsetAsync(rsum, 0, (size_t)M * 4, stream);
    hipMemsetAsync(g0,   0, (size_t)H * 4, stream);

    // 1) converts + transposes + bfinal + distributed-atomic g0
    cvt_all<<<10064, 256, 0, stream>>>(x, Wq, Wk, Wo, Wv, bq, bv, bo,
                                       x16, w16, bfin, g0);

    // 2) Gt = G^T = WkT.WqT^T, F = Wo.WvT^T
    gemm_gf<<<128, 256, 0, stream>>>(w16, Gt16, F16);

    // 3) qg = x.Gt^T + g0  and  Vot[b] = F.x_b^T
    gemm_qgv<<<1024, 256, 0, stream>>>(x16, Gt16, F16, g0, qg16, vot16);

    // 4) P_un[b] = exp((qg.x_b^T)/8) + atomic rowsums  (128^2 proven path)
    gemm_sc<<<dim3(S / BN, S / BM, 2), 256, 0, stream>>>(
        qg16, x16, p16, rsum, 0.125f, S, S, 1024,
        (long long)S * H, (long long)S * H, (long long)S * S);

    // 5) out[b] = (P_un . Vot^T)/rowsum + bfinal   (128x256 phase-split)
    gemm8p<128, 256><<<256, 512, 0, stream>>>(
        p16, vot16, out, bfin, rsum, S, H, 4096,
        (long long)S * S, (long long)H * S, (long long)S * H, 32, 4);
}